// Round 1
// baseline (501.856 us; speedup 1.0000x reference)
//
#include <hip/hip_runtime.h>
#include <hip/hip_bf16.h>
#include <math.h>

#define BATCH 2
#define NPTS 4096
#define DIM 128
#define HID 12
#define KNN 16

// ---------------------------------------------------------------------------
// Kernel A: exact KNN (top-16 incl. self) per query point.
// grid = B*N/4 blocks, 256 threads = 4 waves, 1 query per wave.
// d2 computed in f64 (exact for f32 inputs -> true ordering).
// ---------------------------------------------------------------------------
__global__ __launch_bounds__(256) void knn_kernel(const float* __restrict__ pos,
                                                  int* __restrict__ knn_out) {
  __shared__ float pos_s[NPTS * 3];  // 48 KB
  const int t = threadIdx.x;
  const int b = blockIdx.x >> 10;            // 1024 blocks per batch
  const int n0 = (blockIdx.x & 1023) << 2;   // 4 queries per block
  const int w = t >> 6;
  const int lane = t & 63;

  for (int i = t; i < NPTS * 3; i += 256) pos_s[i] = pos[b * NPTS * 3 + i];
  __syncthreads();

  const int n = n0 + w;
  const double qx = (double)pos_s[n * 3 + 0];
  const double qy = (double)pos_s[n * 3 + 1];
  const double qz = (double)pos_s[n * 3 + 2];

  double bd[16];
  int bi[16];
#pragma unroll
  for (int j = 0; j < 16; ++j) { bd[j] = 1e300; bi[j] = 0x7fffffff; }

  for (int m = lane; m < NPTS; m += 64) {
    const double dx = qx - (double)pos_s[m * 3 + 0];
    const double dy = qy - (double)pos_s[m * 3 + 1];
    const double dz = qz - (double)pos_s[m * 3 + 2];
    const double d2 = dx * dx + dy * dy + dz * dz;
    if (d2 < bd[15]) {
      // unrolled insertion into sorted ascending list (stable: ties keep older)
#pragma unroll
      for (int j = 15; j > 0; --j) {
        if (d2 < bd[j - 1]) { bd[j] = bd[j - 1]; bi[j] = bi[j - 1]; }
        else if (d2 < bd[j]) { bd[j] = d2; bi[j] = m; }
      }
      if (d2 < bd[0]) { bd[0] = d2; bi[0] = m; }
    }
  }

  // merge 64 per-lane sorted lists: 16 rounds of wave-argmin + pop-front
  const int out_base = ((b << 12) + n) * KNN;
#pragma unroll 1
  for (int r = 0; r < KNN; ++r) {
    double best = bd[0];
    int bid = bi[0];
#pragma unroll
    for (int off = 32; off >= 1; off >>= 1) {
      const double ov = __shfl_xor(best, off);
      const int oi = __shfl_xor(bid, off);
      if (ov < best || (ov == best && oi < bid)) { best = ov; bid = oi; }
    }
    if (lane == 0) knn_out[out_base + r] = bid;
    if (bd[0] == best && bi[0] == bid) {
#pragma unroll
      for (int j = 0; j < 15; ++j) { bd[j] = bd[j + 1]; bi[j] = bi[j + 1]; }
      bd[15] = 1e300; bi[15] = 0x7fffffff;
    }
  }
}

// ---------------------------------------------------------------------------
// Kernel B: q/k/v projections: (8192 x 128) @ (128 x 128)^T  x3
// grid = B*N/8 blocks, 256 threads. 8 rows per block, x staged in LDS.
// ---------------------------------------------------------------------------
__device__ __forceinline__ void proj4(const float xs[8][DIM], const float* __restrict__ w,
                                      float* __restrict__ o, int r0, int c, int rg) {
  const float4* wrow = (const float4*)(w + c * DIM);
  float a0 = 0.f, a1 = 0.f, a2 = 0.f, a3 = 0.f;
#pragma unroll 8
  for (int i = 0; i < 32; ++i) {
    const float4 w4 = wrow[i];
    const float4 x0 = ((const float4*)xs[rg * 4 + 0])[i];
    const float4 x1 = ((const float4*)xs[rg * 4 + 1])[i];
    const float4 x2 = ((const float4*)xs[rg * 4 + 2])[i];
    const float4 x3 = ((const float4*)xs[rg * 4 + 3])[i];
    a0 = fmaf(w4.x, x0.x, fmaf(w4.y, x0.y, fmaf(w4.z, x0.z, fmaf(w4.w, x0.w, a0))));
    a1 = fmaf(w4.x, x1.x, fmaf(w4.y, x1.y, fmaf(w4.z, x1.z, fmaf(w4.w, x1.w, a1))));
    a2 = fmaf(w4.x, x2.x, fmaf(w4.y, x2.y, fmaf(w4.z, x2.z, fmaf(w4.w, x2.w, a2))));
    a3 = fmaf(w4.x, x3.x, fmaf(w4.y, x3.y, fmaf(w4.z, x3.z, fmaf(w4.w, x3.w, a3))));
  }
  o[(r0 + rg * 4 + 0) * DIM + c] = a0;
  o[(r0 + rg * 4 + 1) * DIM + c] = a1;
  o[(r0 + rg * 4 + 2) * DIM + c] = a2;
  o[(r0 + rg * 4 + 3) * DIM + c] = a3;
}

__global__ __launch_bounds__(256) void qkv_kernel(const float* __restrict__ x,
                                                  const float* __restrict__ wq,
                                                  const float* __restrict__ wk,
                                                  const float* __restrict__ wv,
                                                  float* __restrict__ qp,
                                                  float* __restrict__ kp,
                                                  float* __restrict__ vp) {
  __shared__ float xs[8][DIM];
  const int t = threadIdx.x;
  const int r0 = blockIdx.x * 8;
  for (int i = t; i < 8 * DIM; i += 256) xs[i >> 7][i & 127] = x[r0 * DIM + i];
  __syncthreads();
  const int c = t & 127, rg = t >> 7;
  proj4(xs, wq, qp, r0, c, rg);
  proj4(xs, wk, kp, r0, c, rg);
  proj4(xs, wv, vp, r0, c, rg);
}

// ---------------------------------------------------------------------------
// Kernel C: main fused kernel, one block per (b,n).
// ---------------------------------------------------------------------------
__device__ __forceinline__ void layer_matmul(const float (*src)[DIM], float (*dst)[DIM],
                                             const float* __restrict__ w,
                                             const float* __restrict__ bias, int t) {
  // 2048 outputs (16 k x 128 e), 256 threads: thread -> e = t&127, 8 k's.
  const int e = t & 127;
  const int k0 = (t >> 7) * 8;
  const float4* wrow = (const float4*)(w + e * DIM);
  float acc[8] = {0.f, 0.f, 0.f, 0.f, 0.f, 0.f, 0.f, 0.f};
#pragma unroll 4
  for (int i = 0; i < 32; ++i) {
    const float4 w4 = wrow[i];  // global, L2-hot; sequential lines per lane
#pragma unroll
    for (int kj = 0; kj < 8; ++kj) {
      const float4 a4 = ((const float4*)(src[k0 + kj]))[i];  // LDS broadcast
      acc[kj] = fmaf(w4.x, a4.x, fmaf(w4.y, a4.y, fmaf(w4.z, a4.z, fmaf(w4.w, a4.w, acc[kj]))));
    }
  }
  const float bb = bias[e];
#pragma unroll
  for (int kj = 0; kj < 8; ++kj) dst[k0 + kj][e] = acc[kj] + bb;
}

__device__ __forceinline__ void ln_relu_128(float (*buf)[DIM], const float* __restrict__ g,
                                            const float* __restrict__ beta, int t) {
  // 16 k rows x 128: 16-lane group per k, 8 elems per lane.
  const int k = t >> 4, l = t & 15;
  float v[8];
  float sum = 0.f;
#pragma unroll
  for (int i = 0; i < 8; ++i) { v[i] = buf[k][l + 16 * i]; sum += v[i]; }
#pragma unroll
  for (int off = 8; off >= 1; off >>= 1) sum += __shfl_xor(sum, off);
  const float mu = sum * (1.f / 128.f);
  float var = 0.f;
#pragma unroll
  for (int i = 0; i < 8; ++i) { const float z = v[i] - mu; var = fmaf(z, z, var); }
#pragma unroll
  for (int off = 8; off >= 1; off >>= 1) var += __shfl_xor(var, off);
  const float rs = rsqrtf(var * (1.f / 128.f) + 1e-5f);
#pragma unroll
  for (int i = 0; i < 8; ++i) {
    const int e = l + 16 * i;
    const float z = fmaf((v[i] - mu) * rs, g[e], beta[e]);
    buf[k][e] = fmaxf(z, 0.f);
  }
}

__global__ __launch_bounds__(256) void pt_main_kernel(
    const float* __restrict__ pos, const int* __restrict__ knn_in,
    const float* __restrict__ qp, const float* __restrict__ kp, const float* __restrict__ vp,
    const float* __restrict__ pw1, const float* __restrict__ pb1,
    const float* __restrict__ pg, const float* __restrict__ pbeta,
    const float* __restrict__ pw2, const float* __restrict__ pb2,
    const float* __restrict__ aw1, const float* __restrict__ ab1,
    const float* __restrict__ ag, const float* __restrict__ abeta,
    const float* __restrict__ aw2, const float* __restrict__ ab2,
    float* __restrict__ out) {
  __shared__ float q_s[DIM];
  __shared__ float pe_s[KNN][DIM];
  __shared__ float a_s[KNN][DIM];
  __shared__ float b_s[KNN][DIM];
  __shared__ float pr_s[KNN][4];
  __shared__ float h_s[KNN][HID];
  __shared__ int idx_s[KNN];

  const int t = threadIdx.x;
  const int bn = blockIdx.x;
  const int b = bn >> 12, n = bn & 4095;

  if (t < DIM) q_s[t] = qp[bn * DIM + t];
  if (t >= 128 && t < 128 + KNN) idx_s[t - 128] = knn_in[bn * KNN + (t - 128)];
  __syncthreads();

  const int d = t & 127, kk = t >> 7;
  // a_s = q - kf  (gathered), pos_rel
#pragma unroll
  for (int k = kk; k < KNN; k += 2) {
    const int j = idx_s[k];
    a_s[k][d] = q_s[d] - kp[(b * NPTS + j) * DIM + d];
  }
  if (t < 64) {
    const int k = t >> 2, c = t & 3;
    if (c < 3)
      pr_s[k][c] = pos[(b * NPTS + n) * 3 + c] - pos[(b * NPTS + idx_s[k]) * 3 + c];
  }
  __syncthreads();

  // pos_mlp layer 1 (3 -> 12)
  if (t < KNN * HID) {
    const int k = t / HID, h = t - k * HID;
    const float s = pb1[h] + pr_s[k][0] * pw1[h * 3 + 0] + pr_s[k][1] * pw1[h * 3 + 1] +
                    pr_s[k][2] * pw1[h * 3 + 2];
    h_s[k][h] = s;
  }
  __syncthreads();
  // LN(12) + relu, one thread per k (12 elems serial)
  if (t < KNN) {
    float mu = 0.f;
#pragma unroll
    for (int h = 0; h < HID; ++h) mu += h_s[t][h];
    mu *= (1.f / HID);
    float var = 0.f;
#pragma unroll
    for (int h = 0; h < HID; ++h) { const float z = h_s[t][h] - mu; var = fmaf(z, z, var); }
    const float rs = rsqrtf(var * (1.f / HID) + 1e-5f);
#pragma unroll
    for (int h = 0; h < HID; ++h) {
      const float z = fmaf((h_s[t][h] - mu) * rs, pg[h], pbeta[h]);
      h_s[t][h] = fmaxf(z, 0.f);
    }
  }
  __syncthreads();

  // pe = relu(LN(..)) @ pos_w2.T + pos_b2 ; complete a_s = q - kf + pe
#pragma unroll
  for (int k = kk; k < KNN; k += 2) {
    float s = pb2[d];
#pragma unroll
    for (int h = 0; h < HID; ++h) s = fmaf(h_s[k][h], pw2[d * HID + h], s);
    pe_s[k][d] = s;
    a_s[k][d] += s;
  }
  __syncthreads();

  // attn_mlp: Linear -> LN -> ReLU -> Linear
  layer_matmul(a_s, b_s, aw1, ab1, t);
  __syncthreads();
  ln_relu_128(b_s, ag, abeta, t);
  __syncthreads();
  layer_matmul(b_s, a_s, aw2, ab2, t);
  __syncthreads();

  // softmax over k, weighted sum of (vf + pe)
  if (t < DIM) {
    float wv[KNN];
    float m = -1e30f;
#pragma unroll
    for (int k = 0; k < KNN; ++k) { wv[k] = a_s[k][t]; m = fmaxf(m, wv[k]); }
    float s = 0.f;
#pragma unroll
    for (int k = 0; k < KNN; ++k) { wv[k] = expf(wv[k] - m); s += wv[k]; }
    const float inv = 1.f / s;
    float o = 0.f;
#pragma unroll
    for (int k = 0; k < KNN; ++k) {
      const int j = idx_s[k];
      const float vf = vp[(b * NPTS + j) * DIM + t];
      o = fmaf(wv[k] * inv, vf + pe_s[k][t], o);
    }
    out[bn * DIM + t] = o;
  }
}

// ---------------------------------------------------------------------------
extern "C" void kernel_launch(void* const* d_in, const int* in_sizes, int n_in,
                              void* d_out, int out_size, void* d_ws, size_t ws_size,
                              hipStream_t stream) {
  const float* x    = (const float*)d_in[0];
  const float* pos  = (const float*)d_in[1];
  const float* wq   = (const float*)d_in[2];
  const float* wk   = (const float*)d_in[3];
  const float* wv   = (const float*)d_in[4];
  const float* pw1  = (const float*)d_in[5];
  const float* pb1  = (const float*)d_in[6];
  const float* pg   = (const float*)d_in[7];
  const float* pbt  = (const float*)d_in[8];
  const float* pw2  = (const float*)d_in[9];
  const float* pb2  = (const float*)d_in[10];
  const float* aw1  = (const float*)d_in[11];
  const float* ab1  = (const float*)d_in[12];
  const float* ag   = (const float*)d_in[13];
  const float* abt  = (const float*)d_in[14];
  const float* aw2  = (const float*)d_in[15];
  const float* ab2  = (const float*)d_in[16];
  float* out = (float*)d_out;

  char* ws = (char*)d_ws;
  int*   knn = (int*)ws;                         // 512 KB used
  float* qp  = (float*)(ws + (1u << 20));        // 4 MB
  float* kp  = (float*)(ws + 5u * (1u << 20));   // 4 MB
  float* vp  = (float*)(ws + 9u * (1u << 20));   // 4 MB

  knn_kernel<<<BATCH * NPTS / 4, 256, 0, stream>>>(pos, knn);
  qkv_kernel<<<BATCH * NPTS / 8, 256, 0, stream>>>(x, wq, wk, wv, qp, kp, vp);
  pt_main_kernel<<<BATCH * NPTS, 256, 0, stream>>>(pos, knn, qp, kp, vp,
                                                   pw1, pb1, pg, pbt, pw2, pb2,
                                                   aw1, ab1, ag, abt, aw2, ab2, out);
}

// Round 2
// 351.356 us; speedup vs baseline: 1.4283x; 1.4283x over previous
//
#include <hip/hip_runtime.h>
#include <hip/hip_bf16.h>
#include <math.h>

#define BATCH 2
#define NPTS 4096
#define DIM 128
#define HID 12
#define KNN 16

typedef __attribute__((ext_vector_type(8))) short short8;
typedef __attribute__((ext_vector_type(4))) float f32x4;

// f32 -> bf16 round-to-nearest-even (finite values only)
__device__ __forceinline__ short f2b(float f) {
  unsigned u = __float_as_uint(f);
  unsigned r = (u + 0x7fffu + ((u >> 16) & 1u)) >> 16;
  return (short)r;
}

// ---------------------------------------------------------------------------
// Kernel A: exact KNN (top-16 incl. self) per query point. (unchanged)
// ---------------------------------------------------------------------------
__global__ __launch_bounds__(256) void knn_kernel(const float* __restrict__ pos,
                                                  int* __restrict__ knn_out) {
  __shared__ float pos_s[NPTS * 3];  // 48 KB
  const int t = threadIdx.x;
  const int b = blockIdx.x >> 10;
  const int n0 = (blockIdx.x & 1023) << 2;
  const int w = t >> 6;
  const int lane = t & 63;

  for (int i = t; i < NPTS * 3; i += 256) pos_s[i] = pos[b * NPTS * 3 + i];
  __syncthreads();

  const int n = n0 + w;
  const double qx = (double)pos_s[n * 3 + 0];
  const double qy = (double)pos_s[n * 3 + 1];
  const double qz = (double)pos_s[n * 3 + 2];

  double bd[16];
  int bi[16];
#pragma unroll
  for (int j = 0; j < 16; ++j) { bd[j] = 1e300; bi[j] = 0x7fffffff; }

  for (int m = lane; m < NPTS; m += 64) {
    const double dx = qx - (double)pos_s[m * 3 + 0];
    const double dy = qy - (double)pos_s[m * 3 + 1];
    const double dz = qz - (double)pos_s[m * 3 + 2];
    const double d2 = dx * dx + dy * dy + dz * dz;
    if (d2 < bd[15]) {
#pragma unroll
      for (int j = 15; j > 0; --j) {
        if (d2 < bd[j - 1]) { bd[j] = bd[j - 1]; bi[j] = bi[j - 1]; }
        else if (d2 < bd[j]) { bd[j] = d2; bi[j] = m; }
      }
      if (d2 < bd[0]) { bd[0] = d2; bi[0] = m; }
    }
  }

  const int out_base = ((b << 12) + n) * KNN;
#pragma unroll 1
  for (int r = 0; r < KNN; ++r) {
    double best = bd[0];
    int bid = bi[0];
#pragma unroll
    for (int off = 32; off >= 1; off >>= 1) {
      const double ov = __shfl_xor(best, off);
      const int oi = __shfl_xor(bid, off);
      if (ov < best || (ov == best && oi < bid)) { best = ov; bid = oi; }
    }
    if (lane == 0) knn_out[out_base + r] = bid;
    if (bd[0] == best && bi[0] == bid) {
#pragma unroll
      for (int j = 0; j < 15; ++j) { bd[j] = bd[j + 1]; bi[j] = bi[j + 1]; }
      bd[15] = 1e300; bi[15] = 0x7fffffff;
    }
  }
}

// ---------------------------------------------------------------------------
// Weight folding: Wqa = aw1@wq, Wka = aw1@wk  (each 128x128). grid=128.
// ---------------------------------------------------------------------------
__global__ __launch_bounds__(256) void fold_kernel(const float* __restrict__ aw1,
                                                   const float* __restrict__ wq,
                                                   const float* __restrict__ wk,
                                                   float* __restrict__ Wqa,
                                                   float* __restrict__ Wka) {
  const int bid = blockIdx.x;
  const float* w = (bid < 64) ? wq : wk;
  float* o = (bid < 64) ? Wqa : Wka;
  const int row = ((bid & 63) << 1) + (threadIdx.x >> 7);
  const int i = threadIdx.x & 127;
  float acc = 0.f;
  for (int j = 0; j < 128; ++j) acc = fmaf(aw1[row * 128 + j], w[j * 128 + i], acc);
  o[row * 128 + i] = acc;
}

// ---------------------------------------------------------------------------
// Pack: M1b = bf16(aw1@pw2) [128][32 padded], pw2b = bf16(pw2) [128][32],
// aw2b = bf16(aw2) [128][128], c1 = aw1@pb2 + ab1. grid=4.
// ---------------------------------------------------------------------------
__global__ __launch_bounds__(256) void pack_kernel(
    const float* __restrict__ aw1, const float* __restrict__ pw2,
    const float* __restrict__ pb2, const float* __restrict__ ab1,
    const float* __restrict__ aw2,
    short* __restrict__ M1b, short* __restrict__ pw2b, short* __restrict__ aw2b,
    float* __restrict__ c1) {
  const int bid = blockIdx.x, t = threadIdx.x;
  if (bid == 0) {
    const int o = t >> 1, half = t & 1;
    for (int kk = 0; kk < 16; ++kk) {
      const int k = half * 16 + kk;
      float v = 0.f;
      if (k < HID)
        for (int j = 0; j < 128; ++j) v = fmaf(aw1[o * 128 + j], pw2[j * HID + k], v);
      M1b[o * 32 + k] = (k < HID) ? f2b(v) : (short)0;
    }
    if (t < 128) {
      float v = ab1[t];
      for (int j = 0; j < 128; ++j) v = fmaf(aw1[t * 128 + j], pb2[j], v);
      c1[t] = v;
    }
  } else if (bid == 1) {
    for (int i = t; i < 128 * 32; i += 256) {
      const int o = i >> 5, k = i & 31;
      pw2b[i] = (k < HID) ? f2b(pw2[o * HID + k]) : (short)0;
    }
  } else {
    const int base = (bid - 2) * 8192;
    for (int i = t; i < 8192; i += 256) aw2b[base + i] = f2b(aw2[base + i]);
  }
}

// ---------------------------------------------------------------------------
// Projections: QA = x@Wqa^T, KA = x@Wka^T, V = x@wv^T. grid = B*N/8.
// ---------------------------------------------------------------------------
__device__ __forceinline__ void proj4(const float xs[8][DIM], const float* __restrict__ w,
                                      float* __restrict__ o, int r0, int c, int rg) {
  const float4* wrow = (const float4*)(w + c * DIM);
  float a0 = 0.f, a1 = 0.f, a2 = 0.f, a3 = 0.f;
#pragma unroll 8
  for (int i = 0; i < 32; ++i) {
    const float4 w4 = wrow[i];
    const float4 x0 = ((const float4*)xs[rg * 4 + 0])[i];
    const float4 x1 = ((const float4*)xs[rg * 4 + 1])[i];
    const float4 x2 = ((const float4*)xs[rg * 4 + 2])[i];
    const float4 x3 = ((const float4*)xs[rg * 4 + 3])[i];
    a0 = fmaf(w4.x, x0.x, fmaf(w4.y, x0.y, fmaf(w4.z, x0.z, fmaf(w4.w, x0.w, a0))));
    a1 = fmaf(w4.x, x1.x, fmaf(w4.y, x1.y, fmaf(w4.z, x1.z, fmaf(w4.w, x1.w, a1))));
    a2 = fmaf(w4.x, x2.x, fmaf(w4.y, x2.y, fmaf(w4.z, x2.z, fmaf(w4.w, x2.w, a2))));
    a3 = fmaf(w4.x, x3.x, fmaf(w4.y, x3.y, fmaf(w4.z, x3.z, fmaf(w4.w, x3.w, a3))));
  }
  o[(r0 + rg * 4 + 0) * DIM + c] = a0;
  o[(r0 + rg * 4 + 1) * DIM + c] = a1;
  o[(r0 + rg * 4 + 2) * DIM + c] = a2;
  o[(r0 + rg * 4 + 3) * DIM + c] = a3;
}

__global__ __launch_bounds__(256) void proj_kernel(const float* __restrict__ x,
                                                   const float* __restrict__ wqa,
                                                   const float* __restrict__ wka,
                                                   const float* __restrict__ wv,
                                                   float* __restrict__ qa,
                                                   float* __restrict__ ka,
                                                   float* __restrict__ vp) {
  __shared__ float xs[8][DIM];
  const int t = threadIdx.x;
  const int r0 = blockIdx.x * 8;
  for (int i = t; i < 8 * DIM; i += 256) xs[i >> 7][i & 127] = x[r0 * DIM + i];
  __syncthreads();
  const int c = t & 127, rg = t >> 7;
  proj4(xs, wqa, qa, r0, c, rg);
  proj4(xs, wka, ka, r0, c, rg);
  proj4(xs, wv, vp, r0, c, rg);
}

// ---------------------------------------------------------------------------
// Main kernel: one wave per query. MFMA for both attn-mlp matmuls.
//  MFMA 16x16x32 bf16 layouts (gfx950, learn_hip-verified):
//   A: row=lane&15, k=(lane>>4)*8+e ; B: col=lane&15, k=(lane>>4)*8+e
//   C/D: col=lane&15, row=(lane>>4)*4+reg
// ---------------------------------------------------------------------------
__global__ __launch_bounds__(256) void pt_wave_kernel(
    const float* __restrict__ pos, const int* __restrict__ knn_in,
    const float* __restrict__ QA, const float* __restrict__ KA, const float* __restrict__ Vp,
    const float* __restrict__ pw1, const float* __restrict__ pb1,
    const float* __restrict__ pg, const float* __restrict__ pbeta,
    const float* __restrict__ pb2,
    const float* __restrict__ ag, const float* __restrict__ abeta,
    const float* __restrict__ ab2, const float* __restrict__ c1,
    const short* __restrict__ M1b, const short* __restrict__ pw2b,
    const short* __restrict__ aw2b,
    float* __restrict__ out) {
  __shared__ __align__(16) short z_s[4][2048];  // per-wave 16x128 bf16, swizzled

  const int t = threadIdx.x;
  const int wid = t >> 6;
  const int lane = t & 63;
  const int r16 = lane & 15;
  const int g4 = lane >> 4;
  const int n = blockIdx.x * 4 + wid;  // flattened (b,n)
  const int b = n >> 12;

  // neighbor indices: jA for A-layout row r16, jC[] for C-layout rows g4*4+reg
  const int jA = knn_in[n * KNN + r16];
  int jC[4];
#pragma unroll
  for (int reg = 0; reg < 4; ++reg) jC[reg] = knn_in[n * KNN + g4 * 4 + reg];

  // pos_rel for row r16
  const float qx = pos[n * 3 + 0], qy = pos[n * 3 + 1], qz = pos[n * 3 + 2];
  const int ja_g = b * NPTS + jA;
  const float rx = qx - pos[ja_g * 3 + 0];
  const float ry = qy - pos[ja_g * 3 + 1];
  const float rz = qz - pos[ja_g * 3 + 2];

  // pos_mlp hidden + LN(12) + relu, in-lane
  float hr[HID];
  {
    float mu = 0.f;
#pragma unroll
    for (int hh = 0; hh < HID; ++hh) {
      const float v = pb1[hh] + rx * pw1[hh * 3 + 0] + ry * pw1[hh * 3 + 1] +
                      rz * pw1[hh * 3 + 2];
      hr[hh] = v;
      mu += v;
    }
    mu *= (1.f / HID);
    float var = 0.f;
#pragma unroll
    for (int hh = 0; hh < HID; ++hh) { const float d = hr[hh] - mu; var = fmaf(d, d, var); }
    const float rs = rsqrtf(var * (1.f / HID) + 1e-5f);
#pragma unroll
    for (int hh = 0; hh < HID; ++hh)
      hr[hh] = fmaxf(fmaf((hr[hh] - mu) * rs, pg[hh], pbeta[hh]), 0.f);
  }

  // A1 fragment: A[r16][k], k=h (12, zero-padded to 32)
  short8 a1 = {0, 0, 0, 0, 0, 0, 0, 0};
  if (g4 == 0) {
#pragma unroll
    for (int e = 0; e < 8; ++e) a1[e] = f2b(hr[e]);
  } else if (g4 == 1) {
#pragma unroll
    for (int e = 0; e < 4; ++e) a1[e] = f2b(hr[8 + e]);
  }

  // MFMA1: accw = hr@M1^T (w1 pos-part), accp = hr@pw2^T (pe without pb2)
  const f32x4 zero4 = {0.f, 0.f, 0.f, 0.f};
  f32x4 accw[8], accp[8];
#pragma unroll
  for (int nt = 0; nt < 8; ++nt) {
    const int boff = (nt * 16 + r16) * 32 + g4 * 8;
    const short8 bm = *(const short8*)(M1b + boff);
    const short8 bp = *(const short8*)(pw2b + boff);
    accw[nt] = __builtin_amdgcn_mfma_f32_16x16x32_bf16(a1, bm, zero4, 0, 0, 0);
    accp[nt] = __builtin_amdgcn_mfma_f32_16x16x32_bf16(a1, bp, zero4, 0, 0, 0);
  }

  // w1 = accw + QA - KA + c1  (C-layout: col o=nt*16+r16, rows g4*4+reg)
  float w1v[8][4];
#pragma unroll
  for (int nt = 0; nt < 8; ++nt) {
    const int o = nt * 16 + r16;
    const float base = QA[n * DIM + o] + c1[o];
#pragma unroll
    for (int reg = 0; reg < 4; ++reg) {
      const float ka = KA[(b * NPTS + jC[reg]) * DIM + o];
      w1v[nt][reg] = accw[nt][reg] + base - ka;
    }
  }

  // LayerNorm over 128 cols per row, relu, bf16-pack to swizzled LDS
  {
    float s1[4] = {0.f, 0.f, 0.f, 0.f};
#pragma unroll
    for (int nt = 0; nt < 8; ++nt)
#pragma unroll
      for (int reg = 0; reg < 4; ++reg) s1[reg] += w1v[nt][reg];
#pragma unroll
    for (int reg = 0; reg < 4; ++reg) {
#pragma unroll
      for (int off = 1; off <= 8; off <<= 1) s1[reg] += __shfl_xor(s1[reg], off);
      s1[reg] *= (1.f / 128.f);
    }
    float s2[4] = {0.f, 0.f, 0.f, 0.f};
#pragma unroll
    for (int nt = 0; nt < 8; ++nt)
#pragma unroll
      for (int reg = 0; reg < 4; ++reg) {
        const float d = w1v[nt][reg] - s1[reg];
        s2[reg] = fmaf(d, d, s2[reg]);
      }
#pragma unroll
    for (int reg = 0; reg < 4; ++reg) {
#pragma unroll
      for (int off = 1; off <= 8; off <<= 1) s2[reg] += __shfl_xor(s2[reg], off);
      s2[reg] = rsqrtf(s2[reg] * (1.f / 128.f) + 1e-5f);
    }
    char* zb = (char*)(&z_s[wid][0]);
#pragma unroll
    for (int nt = 0; nt < 8; ++nt) {
      const int o = nt * 16 + r16;
      const float gam = ag[o], bet = abeta[o];
#pragma unroll
      for (int reg = 0; reg < 4; ++reg) {
        const int rr = g4 * 4 + reg;
        const float zv = fmaxf(fmaf((w1v[nt][reg] - s1[reg]) * s2[reg], gam, bet), 0.f);
        unsigned byte = (unsigned)(rr * 256 + o * 2);
        byte ^= ((unsigned)(rr & 7) << 4) ^ ((unsigned)(rr & 8) << 2);
        *(short*)(zb + byte) = f2b(zv);
      }
    }
  }

  // read A2 fragments (wave-local; drain DS writes first)
  asm volatile("s_waitcnt lgkmcnt(0)" ::: "memory");
  short8 a2[4];
  {
    const char* zb = (const char*)(&z_s[wid][0]);
#pragma unroll
    for (int ks = 0; ks < 4; ++ks) {
      unsigned byte = (unsigned)(r16 * 256 + ks * 64 + g4 * 16);
      byte ^= ((unsigned)(r16 & 7) << 4) ^ ((unsigned)(r16 & 8) << 2);
      a2[ks] = *(const short8*)(zb + byte);
    }
  }

  // MFMA2: w2 = z @ aw2^T   (B-frags from L1-resident bf16 weights)
  f32x4 acc2[8];
#pragma unroll
  for (int nt = 0; nt < 8; ++nt) acc2[nt] = zero4;
#pragma unroll
  for (int nt = 0; nt < 8; ++nt) {
#pragma unroll
    for (int ks = 0; ks < 4; ++ks) {
      const short8 bw = *(const short8*)(aw2b + (nt * 16 + r16) * DIM + ks * 32 + g4 * 8);
      acc2[nt] = __builtin_amdgcn_mfma_f32_16x16x32_bf16(a2[ks], bw, acc2[nt], 0, 0, 0);
    }
  }

  // softmax over k (rows) per column, then weighted sum of (V + pe)
  float ew[8][4], inv[8];
#pragma unroll
  for (int nt = 0; nt < 8; ++nt) {
    const float bb = ab2[nt * 16 + r16];
#pragma unroll
    for (int reg = 0; reg < 4; ++reg) ew[nt][reg] = acc2[nt][reg] + bb;
    float m = fmaxf(fmaxf(ew[nt][0], ew[nt][1]), fmaxf(ew[nt][2], ew[nt][3]));
    m = fmaxf(m, __shfl_xor(m, 16));
    m = fmaxf(m, __shfl_xor(m, 32));
    float s = 0.f;
#pragma unroll
    for (int reg = 0; reg < 4; ++reg) { ew[nt][reg] = __expf(ew[nt][reg] - m); s += ew[nt][reg]; }
    s += __shfl_xor(s, 16);
    s += __shfl_xor(s, 32);
    inv[nt] = 1.f / s;
  }

  float o_acc[8];
#pragma unroll
  for (int nt = 0; nt < 8; ++nt) {
    const int o = nt * 16 + r16;
    const float pb = pb2[o];
    float acc = 0.f;
#pragma unroll
    for (int reg = 0; reg < 4; ++reg) {
      const float vv = Vp[(b * NPTS + jC[reg]) * DIM + o];
      acc = fmaf(ew[nt][reg] * inv[nt], vv + accp[nt][reg] + pb, acc);
    }
    acc += __shfl_xor(acc, 16);
    acc += __shfl_xor(acc, 32);
    o_acc[nt] = acc;
  }
#pragma unroll
  for (int q = 0; q < 2; ++q) {
    const int nt = g4 * 2 + q;
    out[n * DIM + nt * 16 + r16] = o_acc[nt];
  }
}

// ---------------------------------------------------------------------------
extern "C" void kernel_launch(void* const* d_in, const int* in_sizes, int n_in,
                              void* d_out, int out_size, void* d_ws, size_t ws_size,
                              hipStream_t stream) {
  const float* x   = (const float*)d_in[0];
  const float* pos = (const float*)d_in[1];
  const float* wq  = (const float*)d_in[2];
  const float* wk  = (const float*)d_in[3];
  const float* wv  = (const float*)d_in[4];
  const float* pw1 = (const float*)d_in[5];
  const float* pb1 = (const float*)d_in[6];
  const float* pg  = (const float*)d_in[7];
  const float* pbt = (const float*)d_in[8];
  const float* pw2 = (const float*)d_in[9];
  const float* pb2 = (const float*)d_in[10];
  const float* aw1 = (const float*)d_in[11];
  const float* ab1 = (const float*)d_in[12];
  const float* ag  = (const float*)d_in[13];
  const float* abt = (const float*)d_in[14];
  const float* aw2 = (const float*)d_in[15];
  const float* ab2 = (const float*)d_in[16];
  float* out = (float*)d_out;

  char* ws = (char*)d_ws;
  int*   knn  = (int*)ws;                          // 512 KB
  float* Wqa  = (float*)(ws + 512u * 1024u);       // 64 KB
  float* Wka  = (float*)(ws + 576u * 1024u);       // 64 KB
  short* M1b  = (short*)(ws + 640u * 1024u);       // 8 KB
  short* pw2b = (short*)(ws + 648u * 1024u);       // 8 KB
  short* aw2b = (short*)(ws + 656u * 1024u);       // 32 KB
  float* c1   = (float*)(ws + 688u * 1024u);       // 512 B
  float* QA   = (float*)(ws + (1u << 20));         // 4 MB
  float* KA   = (float*)(ws + 5u * (1u << 20));    // 4 MB
  float* Vp   = (float*)(ws + 9u * (1u << 20));    // 4 MB

  knn_kernel<<<BATCH * NPTS / 4, 256, 0, stream>>>(pos, knn);
  fold_kernel<<<128, 256, 0, stream>>>(aw1, wq, wk, Wqa, Wka);
  pack_kernel<<<4, 256, 0, stream>>>(aw1, pw2, pb2, ab1, aw2, M1b, pw2b, aw2b, c1);
  proj_kernel<<<BATCH * NPTS / 8, 256, 0, stream>>>(x, Wqa, Wka, wv, QA, KA, Vp);
  pt_wave_kernel<<<BATCH * NPTS / 4, 256, 0, stream>>>(
      pos, knn, QA, KA, Vp, pw1, pb1, pg, pbt, pb2, ag, abt, ab2, c1, M1b, pw2b, aw2b, out);
}

// Round 3
// 245.909 us; speedup vs baseline: 2.0408x; 1.4288x over previous
//
#include <hip/hip_runtime.h>
#include <hip/hip_bf16.h>
#include <math.h>

#define BATCH 2
#define NPTS 4096
#define DIM 128
#define HID 12
#define KNN 16
#define NSLOT 24  // candidate buffer (top-24 by f32, refined to top-16 by f64)

typedef __attribute__((ext_vector_type(8))) short short8;
typedef __attribute__((ext_vector_type(4))) float f32x4;

// f32 -> bf16 round-to-nearest-even (finite values only)
__device__ __forceinline__ short f2b(float f) {
  unsigned u = __float_as_uint(f);
  unsigned r = (u + 0x7fffu + ((u >> 16) & 1u)) >> 16;
  return (short)r;
}

// ---------------------------------------------------------------------------
// Kernel A: exact KNN (top-16 incl. self) per query point.
// One wave per query. Wave-cooperative selection: distributed sorted top-24
// list in lanes 0..23, shared f32 admission threshold (16th best + slack),
// O(1) shfl-shift inserts, final exact f64 re-rank of the 24 survivors.
// ---------------------------------------------------------------------------
__global__ __launch_bounds__(256) void knn_kernel(const float* __restrict__ pos,
                                                  int* __restrict__ knn_out) {
  __shared__ float px[NPTS], py[NPTS], pz[NPTS];  // 48 KB SoA
  const int t = threadIdx.x;
  const int b = blockIdx.x >> 10;
  const int n0 = (blockIdx.x & 1023) << 2;
  const int w = t >> 6;
  const int lane = t & 63;

  const float* pb = pos + b * NPTS * 3;
  for (int i = t; i < NPTS; i += 256) {
    px[i] = pb[i * 3 + 0];
    py[i] = pb[i * 3 + 1];
    pz[i] = pb[i * 3 + 2];
  }
  __syncthreads();

  const int n = n0 + w;
  const float qx = px[n], qy = py[n], qz = pz[n];

  const bool is_slot = (lane < NSLOT);
  float vald = __builtin_inff();  // this lane's slot value (ascending in lanes 0..23)
  int validx = -1;
  float thr = __builtin_inff();   // wave-uniform admission threshold

#pragma unroll 1
  for (int it = 0; it < NPTS / 64; ++it) {
    const int m = it * 64 + lane;
    const float dx = qx - px[m];
    const float dy = qy - py[m];
    const float dz = qz - pz[m];
    const float d2 = fmaf(dx, dx, fmaf(dy, dy, dz * dz));
    unsigned long long mask = __ballot(d2 < thr);
    while (mask) {
      const int src = (int)__builtin_ctzll(mask);
      mask &= mask - 1;
      const float dc = __shfl(d2, src);  // readlane -> uniform
      if (dc >= thr) continue;           // threshold tightened by earlier event
      const int ic = it * 64 + src;
      // distributed sorted insert (lanes 0..23): shift-down + place
      const float vup = __shfl_up(vald, 1);
      const int iup = __shfl_up(validx, 1);
      const bool less = dc < vald;
      const bool take = less && (lane == 0 || dc >= vup);
      if (is_slot) {
        if (take) { vald = dc; validx = ic; }
        else if (less) { vald = vup; validx = iup; }
      }
      const float v15 = __shfl(vald, 15);
      thr = v15 + v15 * 1e-5f;  // slack >> f32 rounding of d2
    }
  }

  // exact f64 distances for the 24 survivors
  double d2e = 1e300;
  if (is_slot) {
    const double ex = (double)qx - (double)px[validx];
    const double ey = (double)qy - (double)py[validx];
    const double ez = (double)qz - (double)pz[validx];
    d2e = ex * ex + ey * ey + ez * ez;
  }
  // rank by (d2e, idx) among the 24; ranks are distinct 0..23
  int rank = 0;
#pragma unroll 1
  for (int j = 0; j < NSLOT; ++j) {
    const double dj = __shfl(d2e, j);
    const int ij = __shfl(validx, j);
    if (dj < d2e || (dj == d2e && ij < validx)) ++rank;
  }
  if (is_slot && rank < KNN) knn_out[((b << 12) + n) * KNN + rank] = validx;
}

// ---------------------------------------------------------------------------
// Weight folding: Wqa = aw1@wq, Wka = aw1@wk  (each 128x128). grid=128.
// ---------------------------------------------------------------------------
__global__ __launch_bounds__(256) void fold_kernel(const float* __restrict__ aw1,
                                                   const float* __restrict__ wq,
                                                   const float* __restrict__ wk,
                                                   float* __restrict__ Wqa,
                                                   float* __restrict__ Wka) {
  const int bid = blockIdx.x;
  const float* w = (bid < 64) ? wq : wk;
  float* o = (bid < 64) ? Wqa : Wka;
  const int row = ((bid & 63) << 1) + (threadIdx.x >> 7);
  const int i = threadIdx.x & 127;
  float acc = 0.f;
  for (int j = 0; j < 128; ++j) acc = fmaf(aw1[row * 128 + j], w[j * 128 + i], acc);
  o[row * 128 + i] = acc;
}

// ---------------------------------------------------------------------------
// Pack: M1b = bf16(aw1@pw2) [128][32 padded], pw2b = bf16(pw2) [128][32],
// aw2b = bf16(aw2) [128][128], c1 = aw1@pb2 + ab1. grid=4.
// ---------------------------------------------------------------------------
__global__ __launch_bounds__(256) void pack_kernel(
    const float* __restrict__ aw1, const float* __restrict__ pw2,
    const float* __restrict__ pb2, const float* __restrict__ ab1,
    const float* __restrict__ aw2,
    short* __restrict__ M1b, short* __restrict__ pw2b, short* __restrict__ aw2b,
    float* __restrict__ c1) {
  const int bid = blockIdx.x, t = threadIdx.x;
  if (bid == 0) {
    const int o = t >> 1, half = t & 1;
    for (int kk = 0; kk < 16; ++kk) {
      const int k = half * 16 + kk;
      float v = 0.f;
      if (k < HID)
        for (int j = 0; j < 128; ++j) v = fmaf(aw1[o * 128 + j], pw2[j * HID + k], v);
      M1b[o * 32 + k] = (k < HID) ? f2b(v) : (short)0;
    }
    if (t < 128) {
      float v = ab1[t];
      for (int j = 0; j < 128; ++j) v = fmaf(aw1[t * 128 + j], pb2[j], v);
      c1[t] = v;
    }
  } else if (bid == 1) {
    for (int i = t; i < 128 * 32; i += 256) {
      const int o = i >> 5, k = i & 31;
      pw2b[i] = (k < HID) ? f2b(pw2[o * HID + k]) : (short)0;
    }
  } else {
    const int base = (bid - 2) * 8192;
    for (int i = t; i < 8192; i += 256) aw2b[base + i] = f2b(aw2[base + i]);
  }
}

// ---------------------------------------------------------------------------
// Projections: QA = x@Wqa^T, KA = x@Wka^T, V = x@wv^T. grid = B*N/8.
// ---------------------------------------------------------------------------
__device__ __forceinline__ void proj4(const float xs[8][DIM], const float* __restrict__ w,
                                      float* __restrict__ o, int r0, int c, int rg) {
  const float4* wrow = (const float4*)(w + c * DIM);
  float a0 = 0.f, a1 = 0.f, a2 = 0.f, a3 = 0.f;
#pragma unroll 8
  for (int i = 0; i < 32; ++i) {
    const float4 w4 = wrow[i];
    const float4 x0 = ((const float4*)xs[rg * 4 + 0])[i];
    const float4 x1 = ((const float4*)xs[rg * 4 + 1])[i];
    const float4 x2 = ((const float4*)xs[rg * 4 + 2])[i];
    const float4 x3 = ((const float4*)xs[rg * 4 + 3])[i];
    a0 = fmaf(w4.x, x0.x, fmaf(w4.y, x0.y, fmaf(w4.z, x0.z, fmaf(w4.w, x0.w, a0))));
    a1 = fmaf(w4.x, x1.x, fmaf(w4.y, x1.y, fmaf(w4.z, x1.z, fmaf(w4.w, x1.w, a1))));
    a2 = fmaf(w4.x, x2.x, fmaf(w4.y, x2.y, fmaf(w4.z, x2.z, fmaf(w4.w, x2.w, a2))));
    a3 = fmaf(w4.x, x3.x, fmaf(w4.y, x3.y, fmaf(w4.z, x3.z, fmaf(w4.w, x3.w, a3))));
  }
  o[(r0 + rg * 4 + 0) * DIM + c] = a0;
  o[(r0 + rg * 4 + 1) * DIM + c] = a1;
  o[(r0 + rg * 4 + 2) * DIM + c] = a2;
  o[(r0 + rg * 4 + 3) * DIM + c] = a3;
}

__global__ __launch_bounds__(256) void proj_kernel(const float* __restrict__ x,
                                                   const float* __restrict__ wqa,
                                                   const float* __restrict__ wka,
                                                   const float* __restrict__ wv,
                                                   float* __restrict__ qa,
                                                   float* __restrict__ ka,
                                                   float* __restrict__ vp) {
  __shared__ float xs[8][DIM];
  const int t = threadIdx.x;
  const int r0 = blockIdx.x * 8;
  for (int i = t; i < 8 * DIM; i += 256) xs[i >> 7][i & 127] = x[r0 * DIM + i];
  __syncthreads();
  const int c = t & 127, rg = t >> 7;
  proj4(xs, wqa, qa, r0, c, rg);
  proj4(xs, wka, ka, r0, c, rg);
  proj4(xs, wv, vp, r0, c, rg);
}

// ---------------------------------------------------------------------------
// Main kernel: one wave per query. MFMA for both attn-mlp matmuls.
//  MFMA 16x16x32 bf16 layouts (gfx950, learn_hip-verified):
//   A: row=lane&15, k=(lane>>4)*8+e ; B: col=lane&15, k=(lane>>4)*8+e
//   C/D: col=lane&15, row=(lane>>4)*4+reg
// ---------------------------------------------------------------------------
__global__ __launch_bounds__(256) void pt_wave_kernel(
    const float* __restrict__ pos, const int* __restrict__ knn_in,
    const float* __restrict__ QA, const float* __restrict__ KA, const float* __restrict__ Vp,
    const float* __restrict__ pw1, const float* __restrict__ pb1,
    const float* __restrict__ pg, const float* __restrict__ pbeta,
    const float* __restrict__ pb2,
    const float* __restrict__ ag, const float* __restrict__ abeta,
    const float* __restrict__ ab2, const float* __restrict__ c1,
    const short* __restrict__ M1b, const short* __restrict__ pw2b,
    const short* __restrict__ aw2b,
    float* __restrict__ out) {
  __shared__ __align__(16) short z_s[4][2048];  // per-wave 16x128 bf16, swizzled

  const int t = threadIdx.x;
  const int wid = t >> 6;
  const int lane = t & 63;
  const int r16 = lane & 15;
  const int g4 = lane >> 4;
  const int n = blockIdx.x * 4 + wid;  // flattened (b,n)
  const int b = n >> 12;

  // neighbor indices: jA for A-layout row r16, jC[] for C-layout rows g4*4+reg
  const int jA = knn_in[n * KNN + r16];
  int jC[4];
#pragma unroll
  for (int reg = 0; reg < 4; ++reg) jC[reg] = knn_in[n * KNN + g4 * 4 + reg];

  // pos_rel for row r16
  const float qx = pos[n * 3 + 0], qy = pos[n * 3 + 1], qz = pos[n * 3 + 2];
  const int ja_g = b * NPTS + jA;
  const float rx = qx - pos[ja_g * 3 + 0];
  const float ry = qy - pos[ja_g * 3 + 1];
  const float rz = qz - pos[ja_g * 3 + 2];

  // pos_mlp hidden + LN(12) + relu, in-lane
  float hr[HID];
  {
    float mu = 0.f;
#pragma unroll
    for (int hh = 0; hh < HID; ++hh) {
      const float v = pb1[hh] + rx * pw1[hh * 3 + 0] + ry * pw1[hh * 3 + 1] +
                      rz * pw1[hh * 3 + 2];
      hr[hh] = v;
      mu += v;
    }
    mu *= (1.f / HID);
    float var = 0.f;
#pragma unroll
    for (int hh = 0; hh < HID; ++hh) { const float d = hr[hh] - mu; var = fmaf(d, d, var); }
    const float rs = rsqrtf(var * (1.f / HID) + 1e-5f);
#pragma unroll
    for (int hh = 0; hh < HID; ++hh)
      hr[hh] = fmaxf(fmaf((hr[hh] - mu) * rs, pg[hh], pbeta[hh]), 0.f);
  }

  // A1 fragment: A[r16][k], k=h (12, zero-padded to 32)
  short8 a1 = {0, 0, 0, 0, 0, 0, 0, 0};
  if (g4 == 0) {
#pragma unroll
    for (int e = 0; e < 8; ++e) a1[e] = f2b(hr[e]);
  } else if (g4 == 1) {
#pragma unroll
    for (int e = 0; e < 4; ++e) a1[e] = f2b(hr[8 + e]);
  }

  // MFMA1: accw = hr@M1^T (w1 pos-part), accp = hr@pw2^T (pe without pb2)
  const f32x4 zero4 = {0.f, 0.f, 0.f, 0.f};
  f32x4 accw[8], accp[8];
#pragma unroll
  for (int nt = 0; nt < 8; ++nt) {
    const int boff = (nt * 16 + r16) * 32 + g4 * 8;
    const short8 bm = *(const short8*)(M1b + boff);
    const short8 bp = *(const short8*)(pw2b + boff);
    accw[nt] = __builtin_amdgcn_mfma_f32_16x16x32_bf16(a1, bm, zero4, 0, 0, 0);
    accp[nt] = __builtin_amdgcn_mfma_f32_16x16x32_bf16(a1, bp, zero4, 0, 0, 0);
  }

  // w1 = accw + QA - KA + c1  (C-layout: col o=nt*16+r16, rows g4*4+reg)
  float w1v[8][4];
#pragma unroll
  for (int nt = 0; nt < 8; ++nt) {
    const int o = nt * 16 + r16;
    const float base = QA[n * DIM + o] + c1[o];
#pragma unroll
    for (int reg = 0; reg < 4; ++reg) {
      const float ka = KA[(b * NPTS + jC[reg]) * DIM + o];
      w1v[nt][reg] = accw[nt][reg] + base - ka;
    }
  }

  // LayerNorm over 128 cols per row, relu, bf16-pack to swizzled LDS
  {
    float s1[4] = {0.f, 0.f, 0.f, 0.f};
#pragma unroll
    for (int nt = 0; nt < 8; ++nt)
#pragma unroll
      for (int reg = 0; reg < 4; ++reg) s1[reg] += w1v[nt][reg];
#pragma unroll
    for (int reg = 0; reg < 4; ++reg) {
#pragma unroll
      for (int off = 1; off <= 8; off <<= 1) s1[reg] += __shfl_xor(s1[reg], off);
      s1[reg] *= (1.f / 128.f);
    }
    float s2[4] = {0.f, 0.f, 0.f, 0.f};
#pragma unroll
    for (int nt = 0; nt < 8; ++nt)
#pragma unroll
      for (int reg = 0; reg < 4; ++reg) {
        const float d = w1v[nt][reg] - s1[reg];
        s2[reg] = fmaf(d, d, s2[reg]);
      }
#pragma unroll
    for (int reg = 0; reg < 4; ++reg) {
#pragma unroll
      for (int off = 1; off <= 8; off <<= 1) s2[reg] += __shfl_xor(s2[reg], off);
      s2[reg] = rsqrtf(s2[reg] * (1.f / 128.f) + 1e-5f);
    }
    char* zb = (char*)(&z_s[wid][0]);
#pragma unroll
    for (int nt = 0; nt < 8; ++nt) {
      const int o = nt * 16 + r16;
      const float gam = ag[o], bet = abeta[o];
#pragma unroll
      for (int reg = 0; reg < 4; ++reg) {
        const int rr = g4 * 4 + reg;
        const float zv = fmaxf(fmaf((w1v[nt][reg] - s1[reg]) * s2[reg], gam, bet), 0.f);
        unsigned byte = (unsigned)(rr * 256 + o * 2);
        byte ^= ((unsigned)(rr & 7) << 4) ^ ((unsigned)(rr & 8) << 2);
        *(short*)(zb + byte) = f2b(zv);
      }
    }
  }

  // read A2 fragments (wave-local; drain DS writes first)
  asm volatile("s_waitcnt lgkmcnt(0)" ::: "memory");
  short8 a2[4];
  {
    const char* zb = (const char*)(&z_s[wid][0]);
#pragma unroll
    for (int ks = 0; ks < 4; ++ks) {
      unsigned byte = (unsigned)(r16 * 256 + ks * 64 + g4 * 16);
      byte ^= ((unsigned)(r16 & 7) << 4) ^ ((unsigned)(r16 & 8) << 2);
      a2[ks] = *(const short8*)(zb + byte);
    }
  }

  // MFMA2: w2 = z @ aw2^T   (B-frags from L1-resident bf16 weights)
  f32x4 acc2[8];
#pragma unroll
  for (int nt = 0; nt < 8; ++nt) acc2[nt] = zero4;
#pragma unroll
  for (int nt = 0; nt < 8; ++nt) {
#pragma unroll
    for (int ks = 0; ks < 4; ++ks) {
      const short8 bw = *(const short8*)(aw2b + (nt * 16 + r16) * DIM + ks * 32 + g4 * 8);
      acc2[nt] = __builtin_amdgcn_mfma_f32_16x16x32_bf16(a2[ks], bw, acc2[nt], 0, 0, 0);
    }
  }

  // softmax over k (rows) per column, then weighted sum of (V + pe)
  float ew[8][4], inv[8];
#pragma unroll
  for (int nt = 0; nt < 8; ++nt) {
    const float bb = ab2[nt * 16 + r16];
#pragma unroll
    for (int reg = 0; reg < 4; ++reg) ew[nt][reg] = acc2[nt][reg] + bb;
    float m = fmaxf(fmaxf(ew[nt][0], ew[nt][1]), fmaxf(ew[nt][2], ew[nt][3]));
    m = fmaxf(m, __shfl_xor(m, 16));
    m = fmaxf(m, __shfl_xor(m, 32));
    float s = 0.f;
#pragma unroll
    for (int reg = 0; reg < 4; ++reg) { ew[nt][reg] = __expf(ew[nt][reg] - m); s += ew[nt][reg]; }
    s += __shfl_xor(s, 16);
    s += __shfl_xor(s, 32);
    inv[nt] = 1.f / s;
  }

  float o_acc[8];
#pragma unroll
  for (int nt = 0; nt < 8; ++nt) {
    const int o = nt * 16 + r16;
    const float pb = pb2[o];
    float acc = 0.f;
#pragma unroll
    for (int reg = 0; reg < 4; ++reg) {
      const float vv = Vp[(b * NPTS + jC[reg]) * DIM + o];
      acc = fmaf(ew[nt][reg] * inv[nt], vv + accp[nt][reg] + pb, acc);
    }
    acc += __shfl_xor(acc, 16);
    acc += __shfl_xor(acc, 32);
    o_acc[nt] = acc;
  }
#pragma unroll
  for (int q = 0; q < 2; ++q) {
    const int nt = g4 * 2 + q;
    out[n * DIM + nt * 16 + r16] = o_acc[nt];
  }
}

// ---------------------------------------------------------------------------
extern "C" void kernel_launch(void* const* d_in, const int* in_sizes, int n_in,
                              void* d_out, int out_size, void* d_ws, size_t ws_size,
                              hipStream_t stream) {
  const float* x   = (const float*)d_in[0];
  const float* pos = (const float*)d_in[1];
  const float* wq  = (const float*)d_in[2];
  const float* wk  = (const float*)d_in[3];
  const float* wv  = (const float*)d_in[4];
  const float* pw1 = (const float*)d_in[5];
  const float* pb1 = (const float*)d_in[6];
  const float* pg  = (const float*)d_in[7];
  const float* pbt = (const float*)d_in[8];
  const float* pw2 = (const float*)d_in[9];
  const float* pb2 = (const float*)d_in[10];
  const float* aw1 = (const float*)d_in[11];
  const float* ab1 = (const float*)d_in[12];
  const float* ag  = (const float*)d_in[13];
  const float* abt = (const float*)d_in[14];
  const float* aw2 = (const float*)d_in[15];
  const float* ab2 = (const float*)d_in[16];
  float* out = (float*)d_out;

  char* ws = (char*)d_ws;
  int*   knn  = (int*)ws;                          // 512 KB
  float* Wqa  = (float*)(ws + 512u * 1024u);       // 64 KB
  float* Wka  = (float*)(ws + 576u * 1024u);       // 64 KB
  short* M1b  = (short*)(ws + 640u * 1024u);       // 8 KB
  short* pw2b = (short*)(ws + 648u * 1024u);       // 8 KB
  short* aw2b = (short*)(ws + 656u * 1024u);       // 32 KB
  float* c1   = (float*)(ws + 688u * 1024u);       // 512 B
  float* QA   = (float*)(ws + (1u << 20));         // 4 MB
  float* KA   = (float*)(ws + 5u * (1u << 20));    // 4 MB
  float* Vp   = (float*)(ws + 9u * (1u << 20));    // 4 MB

  knn_kernel<<<BATCH * NPTS / 4, 256, 0, stream>>>(pos, knn);
  fold_kernel<<<128, 256, 0, stream>>>(aw1, wq, wk, Wqa, Wka);
  pack_kernel<<<4, 256, 0, stream>>>(aw1, pw2, pb2, ab1, aw2, M1b, pw2b, aw2b, c1);
  proj_kernel<<<BATCH * NPTS / 8, 256, 0, stream>>>(x, Wqa, Wka, wv, QA, KA, Vp);
  pt_wave_kernel<<<BATCH * NPTS / 4, 256, 0, stream>>>(
      pos, knn, QA, KA, Vp, pw1, pb1, pg, pbt, pb2, ag, abt, ab2, c1, M1b, pw2b, aw2b, out);
}

// Round 4
// 199.454 us; speedup vs baseline: 2.5162x; 1.2329x over previous
//
#include <hip/hip_runtime.h>
#include <hip/hip_bf16.h>
#include <math.h>

#define BATCH 2
#define NPTS 4096
#define DIM 128
#define HID 12
#define KNN 16
#define NSLOT 24  // candidate buffer (top-24 by f32, refined to top-16 by f64)

typedef __attribute__((ext_vector_type(8))) short short8;
typedef __attribute__((ext_vector_type(4))) float f32x4;

// f32 -> bf16 round-to-nearest-even (finite values only)
__device__ __forceinline__ short f2b(float f) {
  unsigned u = __float_as_uint(f);
  unsigned r = (u + 0x7fffu + ((u >> 16) & 1u)) >> 16;
  return (short)r;
}

// ---------------------------------------------------------------------------
// Kernel A: exact KNN (top-16 incl. self) per query point.
// One wave per query, no LDS (pos is L2-resident; staging only capped
// occupancy). Tile 0 seeds the sorted top-24 via a full-wave bitonic sort
// (no serial warm-up events); tiles 1..63 use the shared-threshold event
// loop with O(1) distributed inserts; exact f64 re-rank of 24 survivors.
// ---------------------------------------------------------------------------
__global__ __launch_bounds__(256) void knn_kernel(const float* __restrict__ pos,
                                                  int* __restrict__ knn_out) {
  const int t = threadIdx.x;
  const int w = t >> 6;
  const int lane = t & 63;
  const int n = (blockIdx.x << 2) + w;  // flattened (b,n), wave-uniform
  const int b = n >> 12;
  const int qn = n & (NPTS - 1);

  const float* pb = pos + b * NPTS * 3;
  const float qx = pb[qn * 3 + 0];
  const float qy = pb[qn * 3 + 1];
  const float qz = pb[qn * 3 + 2];

  // ---- tile 0: distance + full-wave bitonic sort (ascending by d2) ----
  float v;
  int vi;
  {
    const float dx = qx - pb[lane * 3 + 0];
    const float dy = qy - pb[lane * 3 + 1];
    const float dz = qz - pb[lane * 3 + 2];
    v = fmaf(dx, dx, fmaf(dy, dy, dz * dz));
    vi = lane;
  }
#pragma unroll
  for (int k = 2; k <= 64; k <<= 1) {
#pragma unroll
    for (int j = k >> 1; j >= 1; j >>= 1) {
      const float ov = __shfl_xor(v, j);
      const int oi = __shfl_xor(vi, j);
      const bool up = ((lane & k) == 0);
      const bool lowpos = ((lane & j) == 0);
      const bool keep_min = (lowpos == up);
      const bool take = keep_min ? (ov < v) : (ov > v);
      if (take) { v = ov; vi = oi; }
    }
  }

  const bool is_slot = (lane < NSLOT);
  float vald = is_slot ? v : __builtin_inff();
  int validx = is_slot ? vi : -1;
  const float v15i = __shfl(v, 15);
  float thr = v15i + v15i * 1e-5f;  // slack >> f32 rounding of d2

  // ---- tiles 1..63: shared-threshold event loop ----
#pragma unroll 1
  for (int it = 1; it < NPTS / 64; ++it) {
    const int m = it * 64 + lane;
    const float dx = qx - pb[m * 3 + 0];
    const float dy = qy - pb[m * 3 + 1];
    const float dz = qz - pb[m * 3 + 2];
    const float d2 = fmaf(dx, dx, fmaf(dy, dy, dz * dz));
    unsigned long long mask = __ballot(d2 < thr);
    while (mask) {
      const int src = (int)__builtin_ctzll(mask);
      mask &= mask - 1;
      const float dc = __shfl(d2, src);  // readlane -> uniform
      if (dc >= thr) continue;           // threshold tightened by earlier event
      const int ic = it * 64 + src;
      // distributed sorted insert (lanes 0..23): shift-down + place
      const float vup = __shfl_up(vald, 1);
      const int iup = __shfl_up(validx, 1);
      const bool less = dc < vald;
      const bool take = less && (lane == 0 || dc >= vup);
      if (is_slot) {
        if (take) { vald = dc; validx = ic; }
        else if (less) { vald = vup; validx = iup; }
      }
      const float v15 = __shfl(vald, 15);
      thr = v15 + v15 * 1e-5f;
    }
  }

  // ---- exact f64 re-rank of the 24 survivors ----
  double d2e = 1e300;
  if (is_slot) {
    const double ex = (double)qx - (double)pb[validx * 3 + 0];
    const double ey = (double)qy - (double)pb[validx * 3 + 1];
    const double ez = (double)qz - (double)pb[validx * 3 + 2];
    d2e = ex * ex + ey * ey + ez * ez;
  }
  int rank = 0;
#pragma unroll 1
  for (int j = 0; j < NSLOT; ++j) {
    const double dj = __shfl(d2e, j);
    const int ij = __shfl(validx, j);
    if (dj < d2e || (dj == d2e && ij < validx)) ++rank;
  }
  if (is_slot && rank < KNN) knn_out[((b << 12) + qn) * KNN + rank] = validx;
}

// ---------------------------------------------------------------------------
// Weight folding: Wqa = aw1@wq, Wka = aw1@wk  (each 128x128). grid=128.
// ---------------------------------------------------------------------------
__global__ __launch_bounds__(256) void fold_kernel(const float* __restrict__ aw1,
                                                   const float* __restrict__ wq,
                                                   const float* __restrict__ wk,
                                                   float* __restrict__ Wqa,
                                                   float* __restrict__ Wka) {
  const int bid = blockIdx.x;
  const float* w = (bid < 64) ? wq : wk;
  float* o = (bid < 64) ? Wqa : Wka;
  const int row = ((bid & 63) << 1) + (threadIdx.x >> 7);
  const int i = threadIdx.x & 127;
  float acc = 0.f;
  for (int j = 0; j < 128; ++j) acc = fmaf(aw1[row * 128 + j], w[j * 128 + i], acc);
  o[row * 128 + i] = acc;
}

// ---------------------------------------------------------------------------
// Pack: M1b = bf16(aw1@pw2) [128][32 padded], pw2b = bf16(pw2) [128][32],
// aw2b = bf16(aw2) [128][128], c1 = aw1@pb2 + ab1. grid=4.
// ---------------------------------------------------------------------------
__global__ __launch_bounds__(256) void pack_kernel(
    const float* __restrict__ aw1, const float* __restrict__ pw2,
    const float* __restrict__ pb2, const float* __restrict__ ab1,
    const float* __restrict__ aw2,
    short* __restrict__ M1b, short* __restrict__ pw2b, short* __restrict__ aw2b,
    float* __restrict__ c1) {
  const int bid = blockIdx.x, t = threadIdx.x;
  if (bid == 0) {
    const int o = t >> 1, half = t & 1;
    for (int kk = 0; kk < 16; ++kk) {
      const int k = half * 16 + kk;
      float v = 0.f;
      if (k < HID)
        for (int j = 0; j < 128; ++j) v = fmaf(aw1[o * 128 + j], pw2[j * HID + k], v);
      M1b[o * 32 + k] = (k < HID) ? f2b(v) : (short)0;
    }
    if (t < 128) {
      float v = ab1[t];
      for (int j = 0; j < 128; ++j) v = fmaf(aw1[t * 128 + j], pb2[j], v);
      c1[t] = v;
    }
  } else if (bid == 1) {
    for (int i = t; i < 128 * 32; i += 256) {
      const int o = i >> 5, k = i & 31;
      pw2b[i] = (k < HID) ? f2b(pw2[o * HID + k]) : (short)0;
    }
  } else {
    const int base = (bid - 2) * 8192;
    for (int i = t; i < 8192; i += 256) aw2b[base + i] = f2b(aw2[base + i]);
  }
}

// ---------------------------------------------------------------------------
// Projections: QA = x@Wqa^T, KA = x@Wka^T, V = x@wv^T. grid = B*N/8.
// ---------------------------------------------------------------------------
__device__ __forceinline__ void proj4(const float xs[8][DIM], const float* __restrict__ w,
                                      float* __restrict__ o, int r0, int c, int rg) {
  const float4* wrow = (const float4*)(w + c * DIM);
  float a0 = 0.f, a1 = 0.f, a2 = 0.f, a3 = 0.f;
#pragma unroll 8
  for (int i = 0; i < 32; ++i) {
    const float4 w4 = wrow[i];
    const float4 x0 = ((const float4*)xs[rg * 4 + 0])[i];
    const float4 x1 = ((const float4*)xs[rg * 4 + 1])[i];
    const float4 x2 = ((const float4*)xs[rg * 4 + 2])[i];
    const float4 x3 = ((const float4*)xs[rg * 4 + 3])[i];
    a0 = fmaf(w4.x, x0.x, fmaf(w4.y, x0.y, fmaf(w4.z, x0.z, fmaf(w4.w, x0.w, a0))));
    a1 = fmaf(w4.x, x1.x, fmaf(w4.y, x1.y, fmaf(w4.z, x1.z, fmaf(w4.w, x1.w, a1))));
    a2 = fmaf(w4.x, x2.x, fmaf(w4.y, x2.y, fmaf(w4.z, x2.z, fmaf(w4.w, x2.w, a2))));
    a3 = fmaf(w4.x, x3.x, fmaf(w4.y, x3.y, fmaf(w4.z, x3.z, fmaf(w4.w, x3.w, a3))));
  }
  o[(r0 + rg * 4 + 0) * DIM + c] = a0;
  o[(r0 + rg * 4 + 1) * DIM + c] = a1;
  o[(r0 + rg * 4 + 2) * DIM + c] = a2;
  o[(r0 + rg * 4 + 3) * DIM + c] = a3;
}

__global__ __launch_bounds__(256) void proj_kernel(const float* __restrict__ x,
                                                   const float* __restrict__ wqa,
                                                   const float* __restrict__ wka,
                                                   const float* __restrict__ wv,
                                                   float* __restrict__ qa,
                                                   float* __restrict__ ka,
                                                   float* __restrict__ vp) {
  __shared__ float xs[8][DIM];
  const int t = threadIdx.x;
  const int r0 = blockIdx.x * 8;
  for (int i = t; i < 8 * DIM; i += 256) xs[i >> 7][i & 127] = x[r0 * DIM + i];
  __syncthreads();
  const int c = t & 127, rg = t >> 7;
  proj4(xs, wqa, qa, r0, c, rg);
  proj4(xs, wka, ka, r0, c, rg);
  proj4(xs, wv, vp, r0, c, rg);
}

// ---------------------------------------------------------------------------
// Main kernel: one wave per query. MFMA for both attn-mlp matmuls.
//  MFMA 16x16x32 bf16 layouts (gfx950, learn_hip-verified):
//   A: row=lane&15, k=(lane>>4)*8+e ; B: col=lane&15, k=(lane>>4)*8+e
//   C/D: col=lane&15, row=(lane>>4)*4+reg
// ---------------------------------------------------------------------------
__global__ __launch_bounds__(256) void pt_wave_kernel(
    const float* __restrict__ pos, const int* __restrict__ knn_in,
    const float* __restrict__ QA, const float* __restrict__ KA, const float* __restrict__ Vp,
    const float* __restrict__ pw1, const float* __restrict__ pb1,
    const float* __restrict__ pg, const float* __restrict__ pbeta,
    const float* __restrict__ pb2,
    const float* __restrict__ ag, const float* __restrict__ abeta,
    const float* __restrict__ ab2, const float* __restrict__ c1,
    const short* __restrict__ M1b, const short* __restrict__ pw2b,
    const short* __restrict__ aw2b,
    float* __restrict__ out) {
  __shared__ __align__(16) short z_s[4][2048];  // per-wave 16x128 bf16, swizzled

  const int t = threadIdx.x;
  const int wid = t >> 6;
  const int lane = t & 63;
  const int r16 = lane & 15;
  const int g4 = lane >> 4;
  const int n = blockIdx.x * 4 + wid;  // flattened (b,n)
  const int b = n >> 12;

  // neighbor indices: jA for A-layout row r16, jC[] for C-layout rows g4*4+reg
  const int jA = knn_in[n * KNN + r16];
  int jC[4];
#pragma unroll
  for (int reg = 0; reg < 4; ++reg) jC[reg] = knn_in[n * KNN + g4 * 4 + reg];

  // pos_rel for row r16
  const float qx = pos[n * 3 + 0], qy = pos[n * 3 + 1], qz = pos[n * 3 + 2];
  const int ja_g = b * NPTS + jA;
  const float rx = qx - pos[ja_g * 3 + 0];
  const float ry = qy - pos[ja_g * 3 + 1];
  const float rz = qz - pos[ja_g * 3 + 2];

  // pos_mlp hidden + LN(12) + relu, in-lane
  float hr[HID];
  {
    float mu = 0.f;
#pragma unroll
    for (int hh = 0; hh < HID; ++hh) {
      const float v = pb1[hh] + rx * pw1[hh * 3 + 0] + ry * pw1[hh * 3 + 1] +
                      rz * pw1[hh * 3 + 2];
      hr[hh] = v;
      mu += v;
    }
    mu *= (1.f / HID);
    float var = 0.f;
#pragma unroll
    for (int hh = 0; hh < HID; ++hh) { const float d = hr[hh] - mu; var = fmaf(d, d, var); }
    const float rs = rsqrtf(var * (1.f / HID) + 1e-5f);
#pragma unroll
    for (int hh = 0; hh < HID; ++hh)
      hr[hh] = fmaxf(fmaf((hr[hh] - mu) * rs, pg[hh], pbeta[hh]), 0.f);
  }

  // A1 fragment: A[r16][k], k=h (12, zero-padded to 32)
  short8 a1 = {0, 0, 0, 0, 0, 0, 0, 0};
  if (g4 == 0) {
#pragma unroll
    for (int e = 0; e < 8; ++e) a1[e] = f2b(hr[e]);
  } else if (g4 == 1) {
#pragma unroll
    for (int e = 0; e < 4; ++e) a1[e] = f2b(hr[8 + e]);
  }

  // MFMA1: accw = hr@M1^T (w1 pos-part), accp = hr@pw2^T (pe without pb2)
  const f32x4 zero4 = {0.f, 0.f, 0.f, 0.f};
  f32x4 accw[8], accp[8];
#pragma unroll
  for (int nt = 0; nt < 8; ++nt) {
    const int boff = (nt * 16 + r16) * 32 + g4 * 8;
    const short8 bm = *(const short8*)(M1b + boff);
    const short8 bp = *(const short8*)(pw2b + boff);
    accw[nt] = __builtin_amdgcn_mfma_f32_16x16x32_bf16(a1, bm, zero4, 0, 0, 0);
    accp[nt] = __builtin_amdgcn_mfma_f32_16x16x32_bf16(a1, bp, zero4, 0, 0, 0);
  }

  // w1 = accw + QA - KA + c1  (C-layout: col o=nt*16+r16, rows g4*4+reg)
  float w1v[8][4];
#pragma unroll
  for (int nt = 0; nt < 8; ++nt) {
    const int o = nt * 16 + r16;
    const float base = QA[n * DIM + o] + c1[o];
#pragma unroll
    for (int reg = 0; reg < 4; ++reg) {
      const float ka = KA[(b * NPTS + jC[reg]) * DIM + o];
      w1v[nt][reg] = accw[nt][reg] + base - ka;
    }
  }

  // LayerNorm over 128 cols per row, relu, bf16-pack to swizzled LDS
  {
    float s1[4] = {0.f, 0.f, 0.f, 0.f};
#pragma unroll
    for (int nt = 0; nt < 8; ++nt)
#pragma unroll
      for (int reg = 0; reg < 4; ++reg) s1[reg] += w1v[nt][reg];
#pragma unroll
    for (int reg = 0; reg < 4; ++reg) {
#pragma unroll
      for (int off = 1; off <= 8; off <<= 1) s1[reg] += __shfl_xor(s1[reg], off);
      s1[reg] *= (1.f / 128.f);
    }
    float s2[4] = {0.f, 0.f, 0.f, 0.f};
#pragma unroll
    for (int nt = 0; nt < 8; ++nt)
#pragma unroll
      for (int reg = 0; reg < 4; ++reg) {
        const float d = w1v[nt][reg] - s1[reg];
        s2[reg] = fmaf(d, d, s2[reg]);
      }
#pragma unroll
    for (int reg = 0; reg < 4; ++reg) {
#pragma unroll
      for (int off = 1; off <= 8; off <<= 1) s2[reg] += __shfl_xor(s2[reg], off);
      s2[reg] = rsqrtf(s2[reg] * (1.f / 128.f) + 1e-5f);
    }
    char* zb = (char*)(&z_s[wid][0]);
#pragma unroll
    for (int nt = 0; nt < 8; ++nt) {
      const int o = nt * 16 + r16;
      const float gam = ag[o], bet = abeta[o];
#pragma unroll
      for (int reg = 0; reg < 4; ++reg) {
        const int rr = g4 * 4 + reg;
        const float zv = fmaxf(fmaf((w1v[nt][reg] - s1[reg]) * s2[reg], gam, bet), 0.f);
        unsigned byte = (unsigned)(rr * 256 + o * 2);
        byte ^= ((unsigned)(rr & 7) << 4) ^ ((unsigned)(rr & 8) << 2);
        *(short*)(zb + byte) = f2b(zv);
      }
    }
  }

  // read A2 fragments (wave-local; drain DS writes first)
  asm volatile("s_waitcnt lgkmcnt(0)" ::: "memory");
  short8 a2[4];
  {
    const char* zb = (const char*)(&z_s[wid][0]);
#pragma unroll
    for (int ks = 0; ks < 4; ++ks) {
      unsigned byte = (unsigned)(r16 * 256 + ks * 64 + g4 * 16);
      byte ^= ((unsigned)(r16 & 7) << 4) ^ ((unsigned)(r16 & 8) << 2);
      a2[ks] = *(const short8*)(zb + byte);
    }
  }

  // MFMA2: w2 = z @ aw2^T   (B-frags from L1-resident bf16 weights)
  f32x4 acc2[8];
#pragma unroll
  for (int nt = 0; nt < 8; ++nt) acc2[nt] = zero4;
#pragma unroll
  for (int nt = 0; nt < 8; ++nt) {
#pragma unroll
    for (int ks = 0; ks < 4; ++ks) {
      const short8 bw = *(const short8*)(aw2b + (nt * 16 + r16) * DIM + ks * 32 + g4 * 8);
      acc2[nt] = __builtin_amdgcn_mfma_f32_16x16x32_bf16(a2[ks], bw, acc2[nt], 0, 0, 0);
    }
  }

  // softmax over k (rows) per column, then weighted sum of (V + pe)
  float ew[8][4], inv[8];
#pragma unroll
  for (int nt = 0; nt < 8; ++nt) {
    const float bb = ab2[nt * 16 + r16];
#pragma unroll
    for (int reg = 0; reg < 4; ++reg) ew[nt][reg] = acc2[nt][reg] + bb;
    float m = fmaxf(fmaxf(ew[nt][0], ew[nt][1]), fmaxf(ew[nt][2], ew[nt][3]));
    m = fmaxf(m, __shfl_xor(m, 16));
    m = fmaxf(m, __shfl_xor(m, 32));
    float s = 0.f;
#pragma unroll
    for (int reg = 0; reg < 4; ++reg) { ew[nt][reg] = __expf(ew[nt][reg] - m); s += ew[nt][reg]; }
    s += __shfl_xor(s, 16);
    s += __shfl_xor(s, 32);
    inv[nt] = 1.f / s;
  }

  float o_acc[8];
#pragma unroll
  for (int nt = 0; nt < 8; ++nt) {
    const int o = nt * 16 + r16;
    const float pb = pb2[o];
    float acc = 0.f;
#pragma unroll
    for (int reg = 0; reg < 4; ++reg) {
      const float vv = Vp[(b * NPTS + jC[reg]) * DIM + o];
      acc = fmaf(ew[nt][reg] * inv[nt], vv + accp[nt][reg] + pb, acc);
    }
    acc += __shfl_xor(acc, 16);
    acc += __shfl_xor(acc, 32);
    o_acc[nt] = acc;
  }
#pragma unroll
  for (int q = 0; q < 2; ++q) {
    const int nt = g4 * 2 + q;
    out[n * DIM + nt * 16 + r16] = o_acc[nt];
  }
}

// ---------------------------------------------------------------------------
extern "C" void kernel_launch(void* const* d_in, const int* in_sizes, int n_in,
                              void* d_out, int out_size, void* d_ws, size_t ws_size,
                              hipStream_t stream) {
  const float* x   = (const float*)d_in[0];
  const float* pos = (const float*)d_in[1];
  const float* wq  = (const float*)d_in[2];
  const float* wk  = (const float*)d_in[3];
  const float* wv  = (const float*)d_in[4];
  const float* pw1 = (const float*)d_in[5];
  const float* pb1 = (const float*)d_in[6];
  const float* pg  = (const float*)d_in[7];
  const float* pbt = (const float*)d_in[8];
  const float* pw2 = (const float*)d_in[9];
  const float* pb2 = (const float*)d_in[10];
  const float* aw1 = (const float*)d_in[11];
  const float* ab1 = (const float*)d_in[12];
  const float* ag  = (const float*)d_in[13];
  const float* abt = (const float*)d_in[14];
  const float* aw2 = (const float*)d_in[15];
  const float* ab2 = (const float*)d_in[16];
  float* out = (float*)d_out;

  char* ws = (char*)d_ws;
  int*   knn  = (int*)ws;                          // 512 KB
  float* Wqa  = (float*)(ws + 512u * 1024u);       // 64 KB
  float* Wka  = (float*)(ws + 576u * 1024u);       // 64 KB
  short* M1b  = (short*)(ws + 640u * 1024u);       // 8 KB
  short* pw2b = (short*)(ws + 648u * 1024u);       // 8 KB
  short* aw2b = (short*)(ws + 656u * 1024u);       // 32 KB
  float* c1   = (float*)(ws + 688u * 1024u);       // 512 B
  float* QA   = (float*)(ws + (1u << 20));         // 4 MB
  float* KA   = (float*)(ws + 5u * (1u << 20));    // 4 MB
  float* Vp   = (float*)(ws + 9u * (1u << 20));    // 4 MB

  knn_kernel<<<BATCH * NPTS / 4, 256, 0, stream>>>(pos, knn);
  fold_kernel<<<128, 256, 0, stream>>>(aw1, wq, wk, Wqa, Wka);
  pack_kernel<<<4, 256, 0, stream>>>(aw1, pw2, pb2, ab1, aw2, M1b, pw2b, aw2b, c1);
  proj_kernel<<<BATCH * NPTS / 8, 256, 0, stream>>>(x, Wqa, Wka, wv, QA, KA, Vp);
  pt_wave_kernel<<<BATCH * NPTS / 4, 256, 0, stream>>>(
      pos, knn, QA, KA, Vp, pw1, pb1, pg, pbt, pb2, ag, abt, ab2, c1, M1b, pw2b, aw2b, out);
}

// Round 5
// 176.783 us; speedup vs baseline: 2.8388x; 1.1282x over previous
//
#include <hip/hip_runtime.h>
#include <hip/hip_bf16.h>
#include <math.h>

#define BATCH 2
#define NPTS 4096
#define DIM 128
#define HID 12
#define KNN 16
#define NSLOT 24  // candidate buffer (top-24 by f32, refined to top-16 by f64)

#define KNN_BLOCKS (BATCH * NPTS / 4)  // 2048
#define FOLD_BLOCKS 128
#define PACK_BLOCKS 4

typedef __attribute__((ext_vector_type(8))) short short8;
typedef __attribute__((ext_vector_type(4))) float f32x4;

// f32 -> bf16 round-to-nearest-even (finite values only)
__device__ __forceinline__ short f2b(float f) {
  unsigned u = __float_as_uint(f);
  unsigned r = (u + 0x7fffu + ((u >> 16) & 1u)) >> 16;
  return (short)r;
}

// ---------------------------------------------------------------------------
// KNN body: exact top-16 per query. One wave per query, no LDS.
// Tile 0 seeds sorted top-24 via full-wave bitonic sort; tiles 1..63 use the
// shared-threshold event loop; exact f64 re-rank of 24 survivors.
// ---------------------------------------------------------------------------
__device__ void knn_body(int bid, const float* __restrict__ pos,
                         int* __restrict__ knn_out) {
  const int t = threadIdx.x;
  const int w = t >> 6;
  const int lane = t & 63;
  const int n = (bid << 2) + w;  // flattened (b,n), wave-uniform
  const int b = n >> 12;
  const int qn = n & (NPTS - 1);

  const float* pb = pos + b * NPTS * 3;
  const float qx = pb[qn * 3 + 0];
  const float qy = pb[qn * 3 + 1];
  const float qz = pb[qn * 3 + 2];

  // ---- tile 0: distance + full-wave bitonic sort (ascending by d2) ----
  float v;
  int vi;
  {
    const float dx = qx - pb[lane * 3 + 0];
    const float dy = qy - pb[lane * 3 + 1];
    const float dz = qz - pb[lane * 3 + 2];
    v = fmaf(dx, dx, fmaf(dy, dy, dz * dz));
    vi = lane;
  }
#pragma unroll
  for (int k = 2; k <= 64; k <<= 1) {
#pragma unroll
    for (int j = k >> 1; j >= 1; j >>= 1) {
      const float ov = __shfl_xor(v, j);
      const int oi = __shfl_xor(vi, j);
      const bool up = ((lane & k) == 0);
      const bool lowpos = ((lane & j) == 0);
      const bool keep_min = (lowpos == up);
      const bool take = keep_min ? (ov < v) : (ov > v);
      if (take) { v = ov; vi = oi; }
    }
  }

  const bool is_slot = (lane < NSLOT);
  float vald = is_slot ? v : __builtin_inff();
  int validx = is_slot ? vi : -1;
  const float v15i = __shfl(v, 15);
  float thr = v15i + v15i * 1e-5f;  // slack >> f32 rounding of d2

  // ---- tiles 1..63: shared-threshold event loop ----
#pragma unroll 1
  for (int it = 1; it < NPTS / 64; ++it) {
    const int m = it * 64 + lane;
    const float dx = qx - pb[m * 3 + 0];
    const float dy = qy - pb[m * 3 + 1];
    const float dz = qz - pb[m * 3 + 2];
    const float d2 = fmaf(dx, dx, fmaf(dy, dy, dz * dz));
    unsigned long long mask = __ballot(d2 < thr);
    while (mask) {
      const int src = (int)__builtin_ctzll(mask);
      mask &= mask - 1;
      const float dc = __shfl(d2, src);  // readlane -> uniform
      if (dc >= thr) continue;           // threshold tightened by earlier event
      const int ic = it * 64 + src;
      // distributed sorted insert (lanes 0..23): shift-down + place
      const float vup = __shfl_up(vald, 1);
      const int iup = __shfl_up(validx, 1);
      const bool less = dc < vald;
      const bool take = less && (lane == 0 || dc >= vup);
      if (is_slot) {
        if (take) { vald = dc; validx = ic; }
        else if (less) { vald = vup; validx = iup; }
      }
      const float v15 = __shfl(vald, 15);
      thr = v15 + v15 * 1e-5f;
    }
  }

  // ---- exact f64 re-rank of the 24 survivors ----
  double d2e = 1e300;
  if (is_slot) {
    const double ex = (double)qx - (double)pb[validx * 3 + 0];
    const double ey = (double)qy - (double)pb[validx * 3 + 1];
    const double ez = (double)qz - (double)pb[validx * 3 + 2];
    d2e = ex * ex + ey * ey + ez * ez;
  }
  int rank = 0;
#pragma unroll 1
  for (int j = 0; j < NSLOT; ++j) {
    const double dj = __shfl(d2e, j);
    const int ij = __shfl(validx, j);
    if (dj < d2e || (dj == d2e && ij < validx)) ++rank;
  }
  if (is_slot && rank < KNN) knn_out[((b << 12) + qn) * KNN + rank] = validx;
}

// ---------------------------------------------------------------------------
// Fold body: Wqa = aw1@wq, Wka = aw1@wk  (each 128x128). 128 blocks.
// ---------------------------------------------------------------------------
__device__ void fold_body(int bid, const float* __restrict__ aw1,
                          const float* __restrict__ wq, const float* __restrict__ wk,
                          float* __restrict__ Wqa, float* __restrict__ Wka) {
  const float* w = (bid < 64) ? wq : wk;
  float* o = (bid < 64) ? Wqa : Wka;
  const int row = ((bid & 63) << 1) + (threadIdx.x >> 7);
  const int i = threadIdx.x & 127;
  float acc = 0.f;
  for (int j = 0; j < 128; ++j) acc = fmaf(aw1[row * 128 + j], w[j * 128 + i], acc);
  o[row * 128 + i] = acc;
}

// ---------------------------------------------------------------------------
// Pack body: M1b = bf16(aw1@pw2) [128][32 pad], pw2b = bf16(pw2) [128][32],
// aw2b = bf16(aw2) [128][128], c1 = aw1@pb2 + ab1. 4 blocks.
// ---------------------------------------------------------------------------
__device__ void pack_body(int bid, const float* __restrict__ aw1,
                          const float* __restrict__ pw2, const float* __restrict__ pb2,
                          const float* __restrict__ ab1, const float* __restrict__ aw2,
                          short* __restrict__ M1b, short* __restrict__ pw2b,
                          short* __restrict__ aw2b, float* __restrict__ c1) {
  const int t = threadIdx.x;
  if (bid == 0) {
    const int o = t >> 1, half = t & 1;
    for (int kk = 0; kk < 16; ++kk) {
      const int k = half * 16 + kk;
      float v = 0.f;
      if (k < HID)
        for (int j = 0; j < 128; ++j) v = fmaf(aw1[o * 128 + j], pw2[j * HID + k], v);
      M1b[o * 32 + k] = (k < HID) ? f2b(v) : (short)0;
    }
    if (t < 128) {
      float v = ab1[t];
      for (int j = 0; j < 128; ++j) v = fmaf(aw1[t * 128 + j], pb2[j], v);
      c1[t] = v;
    }
  } else if (bid == 1) {
    for (int i = t; i < 128 * 32; i += 256) {
      const int o = i >> 5, k = i & 31;
      pw2b[i] = (k < HID) ? f2b(pw2[o * HID + k]) : (short)0;
    }
  } else {
    const int base = (bid - 2) * 8192;
    for (int i = t; i < 8192; i += 256) aw2b[base + i] = f2b(aw2[base + i]);
  }
}

// ---------------------------------------------------------------------------
// Launch 1: knn (2048 blocks) || fold (128) || pack (4) — independent work.
// ---------------------------------------------------------------------------
__global__ __launch_bounds__(256) void knn_prep_kernel(
    const float* __restrict__ pos, int* __restrict__ knn_out,
    const float* __restrict__ aw1, const float* __restrict__ wq,
    const float* __restrict__ wk, float* __restrict__ Wqa, float* __restrict__ Wka,
    const float* __restrict__ pw2, const float* __restrict__ pb2,
    const float* __restrict__ ab1, const float* __restrict__ aw2,
    short* __restrict__ M1b, short* __restrict__ pw2b, short* __restrict__ aw2b,
    float* __restrict__ c1) {
  const int bid = blockIdx.x;
  if (bid < KNN_BLOCKS) {
    knn_body(bid, pos, knn_out);
  } else if (bid < KNN_BLOCKS + FOLD_BLOCKS) {
    fold_body(bid - KNN_BLOCKS, aw1, wq, wk, Wqa, Wka);
  } else {
    pack_body(bid - KNN_BLOCKS - FOLD_BLOCKS, aw1, pw2, pb2, ab1, aw2, M1b, pw2b,
              aw2b, c1);
  }
}

// ---------------------------------------------------------------------------
// Launch 2: projections QA = x@Wqa^T, KA = x@Wka^T, V = x@wv^T. grid = B*N/8.
// ---------------------------------------------------------------------------
__device__ __forceinline__ void proj4(const float xs[8][DIM], const float* __restrict__ w,
                                      float* __restrict__ o, int r0, int c, int rg) {
  const float4* wrow = (const float4*)(w + c * DIM);
  float a0 = 0.f, a1 = 0.f, a2 = 0.f, a3 = 0.f;
#pragma unroll 8
  for (int i = 0; i < 32; ++i) {
    const float4 w4 = wrow[i];
    const float4 x0 = ((const float4*)xs[rg * 4 + 0])[i];
    const float4 x1 = ((const float4*)xs[rg * 4 + 1])[i];
    const float4 x2 = ((const float4*)xs[rg * 4 + 2])[i];
    const float4 x3 = ((const float4*)xs[rg * 4 + 3])[i];
    a0 = fmaf(w4.x, x0.x, fmaf(w4.y, x0.y, fmaf(w4.z, x0.z, fmaf(w4.w, x0.w, a0))));
    a1 = fmaf(w4.x, x1.x, fmaf(w4.y, x1.y, fmaf(w4.z, x1.z, fmaf(w4.w, x1.w, a1))));
    a2 = fmaf(w4.x, x2.x, fmaf(w4.y, x2.y, fmaf(w4.z, x2.z, fmaf(w4.w, x2.w, a2))));
    a3 = fmaf(w4.x, x3.x, fmaf(w4.y, x3.y, fmaf(w4.z, x3.z, fmaf(w4.w, x3.w, a3))));
  }
  o[(r0 + rg * 4 + 0) * DIM + c] = a0;
  o[(r0 + rg * 4 + 1) * DIM + c] = a1;
  o[(r0 + rg * 4 + 2) * DIM + c] = a2;
  o[(r0 + rg * 4 + 3) * DIM + c] = a3;
}

__global__ __launch_bounds__(256) void proj_kernel(const float* __restrict__ x,
                                                   const float* __restrict__ wqa,
                                                   const float* __restrict__ wka,
                                                   const float* __restrict__ wv,
                                                   float* __restrict__ qa,
                                                   float* __restrict__ ka,
                                                   float* __restrict__ vp) {
  __shared__ float xs[8][DIM];
  const int t = threadIdx.x;
  const int r0 = blockIdx.x * 8;
  for (int i = t; i < 8 * DIM; i += 256) xs[i >> 7][i & 127] = x[r0 * DIM + i];
  __syncthreads();
  const int c = t & 127, rg = t >> 7;
  proj4(xs, wqa, qa, r0, c, rg);
  proj4(xs, wka, ka, r0, c, rg);
  proj4(xs, wv, vp, r0, c, rg);
}

// ---------------------------------------------------------------------------
// Launch 3: main kernel. ONE BLOCK PER QUERY, 4 waves; wave wid owns column
// tiles nt = 2*wid, 2*wid+1 (32 of 128 cols). Cross-wave LN stats via LDS.
//  MFMA 16x16x32 bf16 layouts (gfx950, learn_hip-verified):
//   A: row=lane&15, k=(lane>>4)*8+e ; B: col=lane&15, k=(lane>>4)*8+e
//   C/D: col=lane&15, row=(lane>>4)*4+reg
// ---------------------------------------------------------------------------
__global__ __launch_bounds__(256) void pt_wave_kernel(
    const float* __restrict__ pos, const int* __restrict__ knn_in,
    const float* __restrict__ QA, const float* __restrict__ KA, const float* __restrict__ Vp,
    const float* __restrict__ pw1, const float* __restrict__ pb1,
    const float* __restrict__ pg, const float* __restrict__ pbeta,
    const float* __restrict__ pb2,
    const float* __restrict__ ag, const float* __restrict__ abeta,
    const float* __restrict__ ab2, const float* __restrict__ c1,
    const short* __restrict__ M1b, const short* __restrict__ pw2b,
    const short* __restrict__ aw2b,
    float* __restrict__ out) {
  __shared__ __align__(16) short z_s[2048];  // 16x128 bf16, XOR-swizzled
  __shared__ float red_s[2][4][16];          // [sum|sumsq][wave][row]

  const int t = threadIdx.x;
  const int wid = t >> 6;
  const int lane = t & 63;
  const int r16 = lane & 15;
  const int g4 = lane >> 4;
  const int n = blockIdx.x;  // flattened (b,n)
  const int b = n >> 12;

  // neighbor indices: jA for A-layout row r16, jC[] for C-layout rows g4*4+reg
  const int jA = knn_in[n * KNN + r16];
  int jC[4];
#pragma unroll
  for (int reg = 0; reg < 4; ++reg) jC[reg] = knn_in[n * KNN + g4 * 4 + reg];

  // pos_rel for row r16
  const float qx = pos[n * 3 + 0], qy = pos[n * 3 + 1], qz = pos[n * 3 + 2];
  const int ja_g = b * NPTS + jA;
  const float rx = qx - pos[ja_g * 3 + 0];
  const float ry = qy - pos[ja_g * 3 + 1];
  const float rz = qz - pos[ja_g * 3 + 2];

  // pos_mlp hidden + LN(12) + relu, in-lane (duplicated across waves - cheap)
  float hr[HID];
  {
    float mu = 0.f;
#pragma unroll
    for (int hh = 0; hh < HID; ++hh) {
      const float v = pb1[hh] + rx * pw1[hh * 3 + 0] + ry * pw1[hh * 3 + 1] +
                      rz * pw1[hh * 3 + 2];
      hr[hh] = v;
      mu += v;
    }
    mu *= (1.f / HID);
    float var = 0.f;
#pragma unroll
    for (int hh = 0; hh < HID; ++hh) { const float d = hr[hh] - mu; var = fmaf(d, d, var); }
    const float rs = rsqrtf(var * (1.f / HID) + 1e-5f);
#pragma unroll
    for (int hh = 0; hh < HID; ++hh)
      hr[hh] = fmaxf(fmaf((hr[hh] - mu) * rs, pg[hh], pbeta[hh]), 0.f);
  }

  // A1 fragment: A[r16][k], k=h (12, zero-padded to 32)
  short8 a1 = {0, 0, 0, 0, 0, 0, 0, 0};
  if (g4 == 0) {
#pragma unroll
    for (int e = 0; e < 8; ++e) a1[e] = f2b(hr[e]);
  } else if (g4 == 1) {
#pragma unroll
    for (int e = 0; e < 4; ++e) a1[e] = f2b(hr[8 + e]);
  }

  // MFMA1 over this wave's 2 col-tiles
  const f32x4 zero4 = {0.f, 0.f, 0.f, 0.f};
  f32x4 accw[2], accp[2];
#pragma unroll
  for (int q = 0; q < 2; ++q) {
    const int boff = ((wid * 2 + q) * 16 + r16) * 32 + g4 * 8;
    const short8 bm = *(const short8*)(M1b + boff);
    const short8 bp = *(const short8*)(pw2b + boff);
    accw[q] = __builtin_amdgcn_mfma_f32_16x16x32_bf16(a1, bm, zero4, 0, 0, 0);
    accp[q] = __builtin_amdgcn_mfma_f32_16x16x32_bf16(a1, bp, zero4, 0, 0, 0);
  }

  // w1 = accw + QA - KA + c1  (C-layout: col o, rows g4*4+reg)
  float w1v[2][4];
#pragma unroll
  for (int q = 0; q < 2; ++q) {
    const int o = (wid * 2 + q) * 16 + r16;
    const float base = QA[n * DIM + o] + c1[o];
#pragma unroll
    for (int reg = 0; reg < 4; ++reg) {
      const float ka = KA[(b * NPTS + jC[reg]) * DIM + o];
      w1v[q][reg] = accw[q][reg] + base - ka;
    }
  }

  // LayerNorm row-stats: per-wave partial (32 cols) then cross-wave LDS reduce
  {
    float ps[4], pq2[4];
#pragma unroll
    for (int reg = 0; reg < 4; ++reg) {
      ps[reg] = w1v[0][reg] + w1v[1][reg];
      pq2[reg] = fmaf(w1v[0][reg], w1v[0][reg], w1v[1][reg] * w1v[1][reg]);
    }
#pragma unroll
    for (int reg = 0; reg < 4; ++reg) {
#pragma unroll
      for (int off = 1; off <= 8; off <<= 1) {
        ps[reg] += __shfl_xor(ps[reg], off);
        pq2[reg] += __shfl_xor(pq2[reg], off);
      }
    }
    if (r16 == 0) {
#pragma unroll
      for (int reg = 0; reg < 4; ++reg) {
        red_s[0][wid][g4 * 4 + reg] = ps[reg];
        red_s[1][wid][g4 * 4 + reg] = pq2[reg];
      }
    }
  }
  __syncthreads();
  float mu[4], rs[4];
#pragma unroll
  for (int reg = 0; reg < 4; ++reg) {
    const int rr = g4 * 4 + reg;
    const float s = red_s[0][0][rr] + red_s[0][1][rr] + red_s[0][2][rr] + red_s[0][3][rr];
    const float q2 = red_s[1][0][rr] + red_s[1][1][rr] + red_s[1][2][rr] + red_s[1][3][rr];
    mu[reg] = s * (1.f / 128.f);
    const float var = q2 * (1.f / 128.f) - mu[reg] * mu[reg];
    rs[reg] = rsqrtf(var + 1e-5f);
  }

  // gamma/relu, bf16-pack this wave's 32 cols into swizzled LDS
  {
    char* zb = (char*)z_s;
#pragma unroll
    for (int q = 0; q < 2; ++q) {
      const int o = (wid * 2 + q) * 16 + r16;
      const float gam = ag[o], bet = abeta[o];
#pragma unroll
      for (int reg = 0; reg < 4; ++reg) {
        const int rr = g4 * 4 + reg;
        const float zv = fmaxf(fmaf((w1v[q][reg] - mu[reg]) * rs[reg], gam, bet), 0.f);
        unsigned byte = (unsigned)(rr * 256 + o * 2);
        byte ^= ((unsigned)(rr & 7) << 4) ^ ((unsigned)(rr & 8) << 2);
        *(short*)(zb + byte) = f2b(zv);
      }
    }
  }
  __syncthreads();

  // A2 fragments: full 128-e range of rows r16
  short8 a2[4];
  {
    const char* zb = (const char*)z_s;
#pragma unroll
    for (int ks = 0; ks < 4; ++ks) {
      unsigned byte = (unsigned)(r16 * 256 + ks * 64 + g4 * 16);
      byte ^= ((unsigned)(r16 & 7) << 4) ^ ((unsigned)(r16 & 8) << 2);
      a2[ks] = *(const short8*)(zb + byte);
    }
  }

  // MFMA2 over this wave's 2 col-tiles (B from L1/L2-hot bf16 weights)
  f32x4 acc2[2] = {zero4, zero4};
#pragma unroll
  for (int q = 0; q < 2; ++q) {
#pragma unroll
    for (int ks = 0; ks < 4; ++ks) {
      const short8 bw =
          *(const short8*)(aw2b + ((wid * 2 + q) * 16 + r16) * DIM + ks * 32 + g4 * 8);
      acc2[q] = __builtin_amdgcn_mfma_f32_16x16x32_bf16(a2[ks], bw, acc2[q], 0, 0, 0);
    }
  }

  // softmax over k (rows = reg x g4 axes) per column, weighted sum of (V + pe)
  float ew[2][4], inv[2];
#pragma unroll
  for (int q = 0; q < 2; ++q) {
    const float bb = ab2[(wid * 2 + q) * 16 + r16];
#pragma unroll
    for (int reg = 0; reg < 4; ++reg) ew[q][reg] = acc2[q][reg] + bb;
    float m = fmaxf(fmaxf(ew[q][0], ew[q][1]), fmaxf(ew[q][2], ew[q][3]));
    m = fmaxf(m, __shfl_xor(m, 16));
    m = fmaxf(m, __shfl_xor(m, 32));
    float s = 0.f;
#pragma unroll
    for (int reg = 0; reg < 4; ++reg) { ew[q][reg] = __expf(ew[q][reg] - m); s += ew[q][reg]; }
    s += __shfl_xor(s, 16);
    s += __shfl_xor(s, 32);
    inv[q] = 1.f / s;
  }

  float o_acc[2];
#pragma unroll
  for (int q = 0; q < 2; ++q) {
    const int o = (wid * 2 + q) * 16 + r16;
    const float pb = pb2[o];
    float acc = 0.f;
#pragma unroll
    for (int reg = 0; reg < 4; ++reg) {
      const float vv = Vp[(b * NPTS + jC[reg]) * DIM + o];
      acc = fmaf(ew[q][reg] * inv[q], vv + accp[q][reg] + pb, acc);
    }
    acc += __shfl_xor(acc, 16);
    acc += __shfl_xor(acc, 32);
    o_acc[q] = acc;
  }
  if (g4 < 2) out[n * DIM + (wid * 2 + g4) * 16 + r16] = o_acc[g4];
}

// ---------------------------------------------------------------------------
extern "C" void kernel_launch(void* const* d_in, const int* in_sizes, int n_in,
                              void* d_out, int out_size, void* d_ws, size_t ws_size,
                              hipStream_t stream) {
  const float* x   = (const float*)d_in[0];
  const float* pos = (const float*)d_in[1];
  const float* wq  = (const float*)d_in[2];
  const float* wk  = (const float*)d_in[3];
  const float* wv  = (const float*)d_in[4];
  const float* pw1 = (const float*)d_in[5];
  const float* pb1 = (const float*)d_in[6];
  const float* pg  = (const float*)d_in[7];
  const float* pbt = (const float*)d_in[8];
  const float* pw2 = (const float*)d_in[9];
  const float* pb2 = (const float*)d_in[10];
  const float* aw1 = (const float*)d_in[11];
  const float* ab1 = (const float*)d_in[12];
  const float* ag  = (const float*)d_in[13];
  const float* abt = (const float*)d_in[14];
  const float* aw2 = (const float*)d_in[15];
  const float* ab2 = (const float*)d_in[16];
  float* out = (float*)d_out;

  char* ws = (char*)d_ws;
  int*   knn  = (int*)ws;                          // 512 KB
  float* Wqa  = (float*)(ws + 512u * 1024u);       // 64 KB
  float* Wka  = (float*)(ws + 576u * 1024u);       // 64 KB
  short* M1b  = (short*)(ws + 640u * 1024u);       // 8 KB
  short* pw2b = (short*)(ws + 648u * 1024u);       // 8 KB
  short* aw2b = (short*)(ws + 656u * 1024u);       // 32 KB
  float* c1   = (float*)(ws + 688u * 1024u);       // 512 B
  float* QA   = (float*)(ws + (1u << 20));         // 4 MB
  float* KA   = (float*)(ws + 5u * (1u << 20));    // 4 MB
  float* Vp   = (float*)(ws + 9u * (1u << 20));    // 4 MB

  knn_prep_kernel<<<KNN_BLOCKS + FOLD_BLOCKS + PACK_BLOCKS, 256, 0, stream>>>(
      pos, knn, aw1, wq, wk, Wqa, Wka, pw2, pb2, ab1, aw2, M1b, pw2b, aw2b, c1);
  proj_kernel<<<BATCH * NPTS / 8, 256, 0, stream>>>(x, Wqa, Wka, wv, QA, KA, Vp);
  pt_wave_kernel<<<BATCH * NPTS, 256, 0, stream>>>(
      pos, knn, QA, KA, Vp, pw1, pb1, pg, pbt, pb2, ag, abt, ab2, c1, M1b, pw2b, aw2b, out);
}

// Round 6
// 140.280 us; speedup vs baseline: 3.5775x; 1.2602x over previous
//
#include <hip/hip_runtime.h>
#include <hip/hip_bf16.h>
#include <math.h>

#define BATCH 2
#define NPTS 4096
#define DIM 128
#define HID 12
#define KNN 16
#define NSLOT 24  // candidate buffer (top-24 by f32, refined to top-16 by f64)

#define KNN_BLOCKS (BATCH * NPTS / 4)  // 2048
#define FOLD_BLOCKS 128
#define PACK_BLOCKS 5

typedef __attribute__((ext_vector_type(8))) short short8;
typedef __attribute__((ext_vector_type(4))) float f32x4;

// f32 -> bf16 round-to-nearest-even (finite values only)
__device__ __forceinline__ short f2b(float f) {
  unsigned u = __float_as_uint(f);
  unsigned r = (u + 0x7fffu + ((u >> 16) & 1u)) >> 16;
  return (short)r;
}
__device__ __forceinline__ float b2f(short h) {
  return __uint_as_float(((unsigned)(unsigned short)h) << 16);
}

// ---------------------------------------------------------------------------
// KNN body: exact top-16 per query. One wave per query, no LDS.
// 2 points per lane per iteration via 3x float2 loads (8B-aligned).
// Seed: bitonic sort of the 64 even points of tile 0; all else via the
// shared-threshold event loop (lazy thr: updated once per event-set).
// Exact f64 re-rank of the 24 survivors at the end.
// ---------------------------------------------------------------------------
#define KNN_EVENTS(d2v, base, odd)                                        \
  {                                                                       \
    unsigned long long mask_ = __ballot((d2v) < thr);                     \
    while (mask_) {                                                       \
      const int src_ = (int)__builtin_ctzll(mask_);                       \
      mask_ &= mask_ - 1;                                                 \
      const float dc_ = __shfl((d2v), src_);                              \
      const int ic_ = (base) + 2 * src_ + (odd);                          \
      const float vup_ = __shfl_up(vald, 1);                              \
      const int iup_ = __shfl_up(validx, 1);                              \
      const bool less_ = dc_ < vald;                                      \
      const bool take_ = less_ && (lane == 0 || dc_ >= vup_);             \
      if (is_slot) {                                                      \
        if (take_) { vald = dc_; validx = ic_; }                          \
        else if (less_) { vald = vup_; validx = iup_; }                   \
      }                                                                   \
    }                                                                     \
    const float v15_ = __shfl(vald, 15);                                  \
    thr = v15_ + v15_ * 1e-5f;                                            \
  }

__device__ void knn_body(int bid, const float* __restrict__ pos,
                         int* __restrict__ knn_out) {
  const int t = threadIdx.x;
  const int w = t >> 6;
  const int lane = t & 63;
  const int n = (bid << 2) + w;  // flattened (b,n), wave-uniform
  const int b = n >> 12;
  const int qn = n & (NPTS - 1);

  const float* pb = pos + b * NPTS * 3;
  const float qx = pb[qn * 3 + 0];
  const float qy = pb[qn * 3 + 1];
  const float qz = pb[qn * 3 + 2];

  // ---- tile 0 (points 0..127): 2 points per lane ----
  float d2a, d2b;
  {
    const float2* pp = (const float2*)(pb + lane * 6);
    const float2 u0 = pp[0], u1 = pp[1], u2 = pp[2];
    float dx = qx - u0.x, dy = qy - u0.y, dz = qz - u1.x;
    d2a = fmaf(dx, dx, fmaf(dy, dy, dz * dz));
    dx = qx - u1.y; dy = qy - u2.x; dz = qz - u2.y;
    d2b = fmaf(dx, dx, fmaf(dy, dy, dz * dz));
  }
  // seed: bitonic sort even-point distances (ascending) across 64 lanes
  float v = d2a;
  int vi = lane * 2;
#pragma unroll
  for (int k = 2; k <= 64; k <<= 1) {
#pragma unroll
    for (int j = k >> 1; j >= 1; j >>= 1) {
      const float ov = __shfl_xor(v, j);
      const int oi = __shfl_xor(vi, j);
      const bool up = ((lane & k) == 0);
      const bool lowpos = ((lane & j) == 0);
      const bool keep_min = (lowpos == up);
      const bool take = keep_min ? (ov < v) : (ov > v);
      if (take) { v = ov; vi = oi; }
    }
  }

  const bool is_slot = (lane < NSLOT);
  float vald = is_slot ? v : __builtin_inff();
  int validx = is_slot ? vi : -1;
  const float v15i = __shfl(v, 15);
  float thr = v15i + v15i * 1e-5f;  // slack >> f32 rounding of d2

  // odd points of tile 0 as events
  KNN_EVENTS(d2b, 0, 1)

  // ---- tiles 1..31 (128 points each) ----
#pragma unroll 1
  for (int it = 1; it < NPTS / 128; ++it) {
    const float2* pp = (const float2*)(pb + it * 384 + lane * 6);
    const float2 u0 = pp[0], u1 = pp[1], u2 = pp[2];
    float dx = qx - u0.x, dy = qy - u0.y, dz = qz - u1.x;
    const float e2a = fmaf(dx, dx, fmaf(dy, dy, dz * dz));
    dx = qx - u1.y; dy = qy - u2.x; dz = qz - u2.y;
    const float e2b = fmaf(dx, dx, fmaf(dy, dy, dz * dz));
    KNN_EVENTS(e2a, it * 128, 0)
    KNN_EVENTS(e2b, it * 128, 1)
  }

  // ---- exact f64 re-rank of the 24 survivors ----
  double d2e = 1e300;
  if (is_slot) {
    const double ex = (double)qx - (double)pb[validx * 3 + 0];
    const double ey = (double)qy - (double)pb[validx * 3 + 1];
    const double ez = (double)qz - (double)pb[validx * 3 + 2];
    d2e = ex * ex + ey * ey + ez * ez;
  }
  int rank = 0;
#pragma unroll 1
  for (int j = 0; j < NSLOT; ++j) {
    const double dj = __shfl(d2e, j);
    const int ij = __shfl(validx, j);
    if (dj < d2e || (dj == d2e && ij < validx)) ++rank;
  }
  if (is_slot && rank < KNN) knn_out[((b << 12) + qn) * KNN + rank] = validx;
}

// ---------------------------------------------------------------------------
// Fold body: Wqa = aw1@wq, Wka = aw1@wk, written directly as bf16 hi/lo
// split (hi = bf16(v), lo = bf16(v - hi)). 128 blocks.
// ---------------------------------------------------------------------------
__device__ void fold_body(int bid, const float* __restrict__ aw1,
                          const float* __restrict__ wq, const float* __restrict__ wk,
                          short* __restrict__ WqaHi, short* __restrict__ WqaLo,
                          short* __restrict__ WkaHi, short* __restrict__ WkaLo) {
  const float* w = (bid < 64) ? wq : wk;
  short* oh = (bid < 64) ? WqaHi : WkaHi;
  short* ol = (bid < 64) ? WqaLo : WkaLo;
  const int row = ((bid & 63) << 1) + (threadIdx.x >> 7);
  const int i = threadIdx.x & 127;
  float acc = 0.f;
  for (int j = 0; j < 128; ++j) acc = fmaf(aw1[row * 128 + j], w[j * 128 + i], acc);
  const short h = f2b(acc);
  oh[row * 128 + i] = h;
  ol[row * 128 + i] = f2b(acc - b2f(h));
}

// ---------------------------------------------------------------------------
// Pack body: M1b = bf16(aw1@pw2) [128][32 pad], pw2b = bf16(pw2) [128][32],
// aw2b = bf16(aw2) [128][128], c1 = aw1@pb2 + ab1, wv -> hi/lo split. 5 blocks.
// ---------------------------------------------------------------------------
__device__ void pack_body(int bid, const float* __restrict__ aw1,
                          const float* __restrict__ pw2, const float* __restrict__ pb2,
                          const float* __restrict__ ab1, const float* __restrict__ aw2,
                          const float* __restrict__ wv,
                          short* __restrict__ M1b, short* __restrict__ pw2b,
                          short* __restrict__ aw2b, float* __restrict__ c1,
                          short* __restrict__ WvHi, short* __restrict__ WvLo) {
  const int t = threadIdx.x;
  if (bid == 0) {
    const int o = t >> 1, half = t & 1;
    for (int kk = 0; kk < 16; ++kk) {
      const int k = half * 16 + kk;
      float v = 0.f;
      if (k < HID)
        for (int j = 0; j < 128; ++j) v = fmaf(aw1[o * 128 + j], pw2[j * HID + k], v);
      M1b[o * 32 + k] = (k < HID) ? f2b(v) : (short)0;
    }
    if (t < 128) {
      float v = ab1[t];
      for (int j = 0; j < 128; ++j) v = fmaf(aw1[t * 128 + j], pb2[j], v);
      c1[t] = v;
    }
  } else if (bid == 1) {
    for (int i = t; i < 128 * 32; i += 256) {
      const int o = i >> 5, k = i & 31;
      pw2b[i] = (k < HID) ? f2b(pw2[o * HID + k]) : (short)0;
    }
  } else if (bid < 4) {
    const int base = (bid - 2) * 8192;
    for (int i = t; i < 8192; i += 256) aw2b[base + i] = f2b(aw2[base + i]);
  } else {
    for (int i = t; i < 128 * 128; i += 256) {
      const float v = wv[i];
      const short h = f2b(v);
      WvHi[i] = h;
      WvLo[i] = f2b(v - b2f(h));
    }
  }
}

// ---------------------------------------------------------------------------
// Launch 1: knn (2048 blocks) || fold (128) || pack (5) — independent work.
// ---------------------------------------------------------------------------
__global__ __launch_bounds__(256) void knn_prep_kernel(
    const float* __restrict__ pos, int* __restrict__ knn_out,
    const float* __restrict__ aw1, const float* __restrict__ wq,
    const float* __restrict__ wk,
    short* __restrict__ WqaHi, short* __restrict__ WqaLo,
    short* __restrict__ WkaHi, short* __restrict__ WkaLo,
    const float* __restrict__ pw2, const float* __restrict__ pb2,
    const float* __restrict__ ab1, const float* __restrict__ aw2,
    const float* __restrict__ wv,
    short* __restrict__ M1b, short* __restrict__ pw2b, short* __restrict__ aw2b,
    float* __restrict__ c1, short* __restrict__ WvHi, short* __restrict__ WvLo) {
  const int bid = blockIdx.x;
  if (bid < KNN_BLOCKS) {
    knn_body(bid, pos, knn_out);
  } else if (bid < KNN_BLOCKS + FOLD_BLOCKS) {
    fold_body(bid - KNN_BLOCKS, aw1, wq, wk, WqaHi, WqaLo, WkaHi, WkaLo);
  } else {
    pack_body(bid - KNN_BLOCKS - FOLD_BLOCKS, aw1, pw2, pb2, ab1, aw2, wv, M1b,
              pw2b, aw2b, c1, WvHi, WvLo);
  }
}

// ---------------------------------------------------------------------------
// Launch 2: MFMA projections with hi/lo bf16 compensation (~f16-accurate).
// QA = x@Wqa^T, KA = x@Wka^T, V = x@wv^T. Block = 32 rows, 4 waves:
// wave w -> rows [ (w>>1)*16 ), col half (w&1). Grid = B*N/32 = 256.
// ---------------------------------------------------------------------------
__global__ __launch_bounds__(256) void proj_mfma_kernel(
    const float* __restrict__ x,
    const short* __restrict__ WqaHi, const short* __restrict__ WqaLo,
    const short* __restrict__ WkaHi, const short* __restrict__ WkaLo,
    const short* __restrict__ WvHi, const short* __restrict__ WvLo,
    float* __restrict__ QA, float* __restrict__ KA, float* __restrict__ Vp) {
  const int t = threadIdx.x;
  const int wid = t >> 6, lane = t & 63;
  const int r16 = lane & 15, g4 = lane >> 4;
  const int rowbase = blockIdx.x * 32 + (wid >> 1) * 16;
  const int ch = wid & 1;

  // A fragments (rows rowbase..rowbase+15), hi/lo split
  short8 ahi[4], alo[4];
#pragma unroll
  for (int ks = 0; ks < 4; ++ks) {
    const float* xp = x + (rowbase + r16) * DIM + ks * 32 + g4 * 8;
#pragma unroll
    for (int e = 0; e < 8; ++e) {
      const float v = xp[e];
      const short h = f2b(v);
      ahi[ks][e] = h;
      alo[ks][e] = f2b(v - b2f(h));
    }
  }

  const f32x4 zero4 = {0.f, 0.f, 0.f, 0.f};
  const short* WH[3] = {WqaHi, WkaHi, WvHi};
  const short* WL[3] = {WqaLo, WkaLo, WvLo};
  float* OUT[3] = {QA, KA, Vp};
#pragma unroll
  for (int mi = 0; mi < 3; ++mi) {
    const short* wh = WH[mi];
    const short* wl = WL[mi];
    float* o = OUT[mi];
#pragma unroll
    for (int q = 0; q < 4; ++q) {
      const int col = (ch * 4 + q) * 16 + r16;
      f32x4 a = zero4;
#pragma unroll
      for (int ks = 0; ks < 4; ++ks) {
        const short8 bh = *(const short8*)(wh + col * DIM + ks * 32 + g4 * 8);
        const short8 bl = *(const short8*)(wl + col * DIM + ks * 32 + g4 * 8);
        a = __builtin_amdgcn_mfma_f32_16x16x32_bf16(ahi[ks], bh, a, 0, 0, 0);
        a = __builtin_amdgcn_mfma_f32_16x16x32_bf16(alo[ks], bh, a, 0, 0, 0);
        a = __builtin_amdgcn_mfma_f32_16x16x32_bf16(ahi[ks], bl, a, 0, 0, 0);
      }
#pragma unroll
      for (int reg = 0; reg < 4; ++reg)
        o[(rowbase + g4 * 4 + reg) * DIM + (ch * 4 + q) * 16 + r16] = a[reg];
    }
  }
}

// ---------------------------------------------------------------------------
// Launch 3: main kernel. ONE BLOCK PER QUERY, 4 waves; wave wid owns column
// tiles nt = 2*wid, 2*wid+1 (32 of 128 cols). Cross-wave LN stats via LDS.
//  MFMA 16x16x32 bf16 layouts (gfx950, learn_hip-verified):
//   A: row=lane&15, k=(lane>>4)*8+e ; B: col=lane&15, k=(lane>>4)*8+e
//   C/D: col=lane&15, row=(lane>>4)*4+reg
// ---------------------------------------------------------------------------
__global__ __launch_bounds__(256) void pt_wave_kernel(
    const float* __restrict__ pos, const int* __restrict__ knn_in,
    const float* __restrict__ QA, const float* __restrict__ KA, const float* __restrict__ Vp,
    const float* __restrict__ pw1, const float* __restrict__ pb1,
    const float* __restrict__ pg, const float* __restrict__ pbeta,
    const float* __restrict__ pb2,
    const float* __restrict__ ag, const float* __restrict__ abeta,
    const float* __restrict__ ab2, const float* __restrict__ c1,
    const short* __restrict__ M1b, const short* __restrict__ pw2b,
    const short* __restrict__ aw2b,
    float* __restrict__ out) {
  __shared__ __align__(16) short z_s[2048];  // 16x128 bf16, XOR-swizzled
  __shared__ float red_s[2][4][16];          // [sum|sumsq][wave][row]

  const int t = threadIdx.x;
  const int wid = t >> 6;
  const int lane = t & 63;
  const int r16 = lane & 15;
  const int g4 = lane >> 4;
  const int n = blockIdx.x;  // flattened (b,n)
  const int b = n >> 12;

  // neighbor indices: jA for A-layout row r16, jC[] for C-layout rows g4*4+reg
  const int jA = knn_in[n * KNN + r16];
  int jC[4];
#pragma unroll
  for (int reg = 0; reg < 4; ++reg) jC[reg] = knn_in[n * KNN + g4 * 4 + reg];

  // pos_rel for row r16
  const float qx = pos[n * 3 + 0], qy = pos[n * 3 + 1], qz = pos[n * 3 + 2];
  const int ja_g = b * NPTS + jA;
  const float rx = qx - pos[ja_g * 3 + 0];
  const float ry = qy - pos[ja_g * 3 + 1];
  const float rz = qz - pos[ja_g * 3 + 2];

  // pos_mlp hidden + LN(12) + relu, in-lane (duplicated across waves - cheap)
  float hr[HID];
  {
    float mu = 0.f;
#pragma unroll
    for (int hh = 0; hh < HID; ++hh) {
      const float v = pb1[hh] + rx * pw1[hh * 3 + 0] + ry * pw1[hh * 3 + 1] +
                      rz * pw1[hh * 3 + 2];
      hr[hh] = v;
      mu += v;
    }
    mu *= (1.f / HID);
    float var = 0.f;
#pragma unroll
    for (int hh = 0; hh < HID; ++hh) { const float d = hr[hh] - mu; var = fmaf(d, d, var); }
    const float rs = rsqrtf(var * (1.f / HID) + 1e-5f);
#pragma unroll
    for (int hh = 0; hh < HID; ++hh)
      hr[hh] = fmaxf(fmaf((hr[hh] - mu) * rs, pg[hh], pbeta[hh]), 0.f);
  }

  // A1 fragment: A[r16][k], k=h (12, zero-padded to 32)
  short8 a1 = {0, 0, 0, 0, 0, 0, 0, 0};
  if (g4 == 0) {
#pragma unroll
    for (int e = 0; e < 8; ++e) a1[e] = f2b(hr[e]);
  } else if (g4 == 1) {
#pragma unroll
    for (int e = 0; e < 4; ++e) a1[e] = f2b(hr[8 + e]);
  }

  // MFMA1 over this wave's 2 col-tiles
  const f32x4 zero4 = {0.f, 0.f, 0.f, 0.f};
  f32x4 accw[2], accp[2];
#pragma unroll
  for (int q = 0; q < 2; ++q) {
    const int boff = ((wid * 2 + q) * 16 + r16) * 32 + g4 * 8;
    const short8 bm = *(const short8*)(M1b + boff);
    const short8 bp = *(const short8*)(pw2b + boff);
    accw[q] = __builtin_amdgcn_mfma_f32_16x16x32_bf16(a1, bm, zero4, 0, 0, 0);
    accp[q] = __builtin_amdgcn_mfma_f32_16x16x32_bf16(a1, bp, zero4, 0, 0, 0);
  }

  // w1 = accw + QA - KA + c1  (C-layout: col o, rows g4*4+reg)
  float w1v[2][4];
#pragma unroll
  for (int q = 0; q < 2; ++q) {
    const int o = (wid * 2 + q) * 16 + r16;
    const float base = QA[n * DIM + o] + c1[o];
#pragma unroll
    for (int reg = 0; reg < 4; ++reg) {
      const float ka = KA[(b * NPTS + jC[reg]) * DIM + o];
      w1v[q][reg] = accw[q][reg] + base - ka;
    }
  }

  // LayerNorm row-stats: per-wave partial (32 cols) then cross-wave LDS reduce
  {
    float ps[4], pq2[4];
#pragma unroll
    for (int reg = 0; reg < 4; ++reg) {
      ps[reg] = w1v[0][reg] + w1v[1][reg];
      pq2[reg] = fmaf(w1v[0][reg], w1v[0][reg], w1v[1][reg] * w1v[1][reg]);
    }
#pragma unroll
    for (int reg = 0; reg < 4; ++reg) {
#pragma unroll
      for (int off = 1; off <= 8; off <<= 1) {
        ps[reg] += __shfl_xor(ps[reg], off);
        pq2[reg] += __shfl_xor(pq2[reg], off);
      }
    }
    if (r16 == 0) {
#pragma unroll
      for (int reg = 0; reg < 4; ++reg) {
        red_s[0][wid][g4 * 4 + reg] = ps[reg];
        red_s[1][wid][g4 * 4 + reg] = pq2[reg];
      }
    }
  }
  __syncthreads();
  float mu[4], rs[4];
#pragma unroll
  for (int reg = 0; reg < 4; ++reg) {
    const int rr = g4 * 4 + reg;
    const float s = red_s[0][0][rr] + red_s[0][1][rr] + red_s[0][2][rr] + red_s[0][3][rr];
    const float q2 = red_s[1][0][rr] + red_s[1][1][rr] + red_s[1][2][rr] + red_s[1][3][rr];
    mu[reg] = s * (1.f / 128.f);
    const float var = q2 * (1.f / 128.f) - mu[reg] * mu[reg];
    rs[reg] = rsqrtf(var + 1e-5f);
  }

  // gamma/relu, bf16-pack this wave's 32 cols into swizzled LDS
  {
    char* zb = (char*)z_s;
#pragma unroll
    for (int q = 0; q < 2; ++q) {
      const int o = (wid * 2 + q) * 16 + r16;
      const float gam = ag[o], bet = abeta[o];
#pragma unroll
      for (int reg = 0; reg < 4; ++reg) {
        const int rr = g4 * 4 + reg;
        const float zv = fmaxf(fmaf((w1v[q][reg] - mu[reg]) * rs[reg], gam, bet), 0.f);
        unsigned byte = (unsigned)(rr * 256 + o * 2);
        byte ^= ((unsigned)(rr & 7) << 4) ^ ((unsigned)(rr & 8) << 2);
        *(short*)(zb + byte) = f2b(zv);
      }
    }
  }
  __syncthreads();

  // A2 fragments: full 128-e range of rows r16
  short8 a2[4];
  {
    const char* zb = (const char*)z_s;
#pragma unroll
    for (int ks = 0; ks < 4; ++ks) {
      unsigned byte = (unsigned)(r16 * 256 + ks * 64 + g4 * 16);
      byte ^= ((unsigned)(r16 & 7) << 4) ^ ((unsigned)(r16 & 8) << 2);
      a2[ks] = *(const short8*)(zb + byte);
    }
  }

  // MFMA2 over this wave's 2 col-tiles (B from L1/L2-hot bf16 weights)
  f32x4 acc2[2] = {zero4, zero4};
#pragma unroll
  for (int q = 0; q < 2; ++q) {
#pragma unroll
    for (int ks = 0; ks < 4; ++ks) {
      const short8 bw =
          *(const short8*)(aw2b + ((wid * 2 + q) * 16 + r16) * DIM + ks * 32 + g4 * 8);
      acc2[q] = __builtin_amdgcn_mfma_f32_16x16x32_bf16(a2[ks], bw, acc2[q], 0, 0, 0);
    }
  }

  // softmax over k (rows = reg x g4 axes) per column, weighted sum of (V + pe)
  float ew[2][4], inv[2];
#pragma unroll
  for (int q = 0; q < 2; ++q) {
    const float bb = ab2[(wid * 2 + q) * 16 + r16];
#pragma unroll
    for (int reg = 0; reg < 4; ++reg) ew[q][reg] = acc2[q][reg] + bb;
    float m = fmaxf(fmaxf(ew[q][0], ew[q][1]), fmaxf(ew[q][2], ew[q][3]));
    m = fmaxf(m, __shfl_xor(m, 16));
    m = fmaxf(m, __shfl_xor(m, 32));
    float s = 0.f;
#pragma unroll
    for (int reg = 0; reg < 4; ++reg) { ew[q][reg] = __expf(ew[q][reg] - m); s += ew[q][reg]; }
    s += __shfl_xor(s, 16);
    s += __shfl_xor(s, 32);
    inv[q] = 1.f / s;
  }

  float o_acc[2];
#pragma unroll
  for (int q = 0; q < 2; ++q) {
    const int o = (wid * 2 + q) * 16 + r16;
    const float pb = pb2[o];
    float acc = 0.f;
#pragma unroll
    for (int reg = 0; reg < 4; ++reg) {
      const float vv = Vp[(b * NPTS + jC[reg]) * DIM + o];
      acc = fmaf(ew[q][reg] * inv[q], vv + accp[q][reg] + pb, acc);
    }
    acc += __shfl_xor(acc, 16);
    acc += __shfl_xor(acc, 32);
    o_acc[q] = acc;
  }
  if (g4 < 2) out[n * DIM + (wid * 2 + g4) * 16 + r16] = o_acc[g4];
}

// ---------------------------------------------------------------------------
extern "C" void kernel_launch(void* const* d_in, const int* in_sizes, int n_in,
                              void* d_out, int out_size, void* d_ws, size_t ws_size,
                              hipStream_t stream) {
  const float* x   = (const float*)d_in[0];
  const float* pos = (const float*)d_in[1];
  const float* wq  = (const float*)d_in[2];
  const float* wk  = (const float*)d_in[3];
  const float* wv  = (const float*)d_in[4];
  const float* pw1 = (const float*)d_in[5];
  const float* pb1 = (const float*)d_in[6];
  const float* pg  = (const float*)d_in[7];
  const float* pbt = (const float*)d_in[8];
  const float* pw2 = (const float*)d_in[9];
  const float* pb2 = (const float*)d_in[10];
  const float* aw1 = (const float*)d_in[11];
  const float* ab1 = (const float*)d_in[12];
  const float* ag  = (const float*)d_in[13];
  const float* abt = (const float*)d_in[14];
  const float* aw2 = (const float*)d_in[15];
  const float* ab2 = (const float*)d_in[16];
  float* out = (float*)d_out;

  char* ws = (char*)d_ws;
  int*   knn   = (int*)ws;                          // 512 KB
  short* WqaHi = (short*)(ws + 512u * 1024u);       // 32 KB
  short* WqaLo = (short*)(ws + 544u * 1024u);       // 32 KB
  short* WkaHi = (short*)(ws + 576u * 1024u);       // 32 KB
  short* WkaLo = (short*)(ws + 608u * 1024u);       // 32 KB
  short* M1b   = (short*)(ws + 640u * 1024u);       // 8 KB
  short* pw2b  = (short*)(ws + 648u * 1024u);       // 8 KB
  short* aw2b  = (short*)(ws + 656u * 1024u);       // 32 KB
  float* c1    = (float*)(ws + 688u * 1024u);       // 512 B
  short* WvHi  = (short*)(ws + 704u * 1024u);       // 32 KB
  short* WvLo  = (short*)(ws + 736u * 1024u);       // 32 KB
  float* QA    = (float*)(ws + (1u << 20));         // 4 MB
  float* KA    = (float*)(ws + 5u * (1u << 20));    // 4 MB
  float* Vp    = (float*)(ws + 9u * (1u << 20));    // 4 MB

  knn_prep_kernel<<<KNN_BLOCKS + FOLD_BLOCKS + PACK_BLOCKS, 256, 0, stream>>>(
      pos, knn, aw1, wq, wk, WqaHi, WqaLo, WkaHi, WkaLo, pw2, pb2, ab1, aw2, wv,
      M1b, pw2b, aw2b, c1, WvHi, WvLo);
  proj_mfma_kernel<<<BATCH * NPTS / 32, 256, 0, stream>>>(
      x, WqaHi, WqaLo, WkaHi, WkaLo, WvHi, WvLo, QA, KA, Vp);
  pt_wave_kernel<<<BATCH * NPTS, 256, 0, stream>>>(
      pos, knn, QA, KA, Vp, pw1, pb1, pg, pbt, pb2, ag, abt, ab2, c1, M1b, pw2b, aw2b, out);
}